// Round 4
// baseline (226.993 us; speedup 1.0000x reference)
//
#include <hip/hip_runtime.h>
#include <hip/hip_bf16.h>

typedef __attribute__((ext_vector_type(8))) short short8;
typedef __attribute__((ext_vector_type(4))) float floatx4;
typedef __attribute__((ext_vector_type(16))) float floatx16;

__device__ __forceinline__ float bf2f(ushort u) {
    return __uint_as_float(((unsigned int)u) << 16);
}
__device__ __forceinline__ ushort f2bf(float f) {
    unsigned int u = __float_as_uint(f);
    unsigned int r = (u + 0x7FFFu + ((u >> 16) & 1u)) >> 16;
    return (ushort)r;
}
// packed f32x2 -> bf16x2
__device__ __forceinline__ unsigned int pk2(float a, float b) {
    union { __hip_bfloat162 h; unsigned int u; } cv;
    cv.h = __float22bfloat162_rn(make_float2(a, b));
    return cv.u;
}
__device__ __forceinline__ float scrub(float v, float lim) {
    return fminf(fmaxf(v, -lim), lim);
}
// async global->LDS, 16B per lane (lane i lands at wave-uniform lds base + 16*i)
__device__ __forceinline__ void glds16(const ushort* g, ushort* l) {
    __builtin_amdgcn_global_load_lds((const __attribute__((address_space(1))) void*)g,
                                     (__attribute__((address_space(3))) void*)l, 16, 0, 0);
}

// Wave-uniform dtype probe on x: bf16 N(0,1) data has exponent byte in [117,131]
// ~99% at even ushort indices; fp32-as-ushort gives ~6%. 32 samples, thr 16.
__device__ __forceinline__ bool detect_bf16(const ushort* __restrict__ probe) {
    const int lane = threadIdx.x & 63;
    ushort u = probe[(lane & 31) * 2];
    int e = (u >> 7) & 0xFF;
    bool pl = (e >= 117) && (e <= 131) && (lane < 32);
    return __popcll(__ballot(pl)) >= 16;
}

// ---------------------------------------------------------------------------
// Transpose helper (256 threads).
// ---------------------------------------------------------------------------
__device__ __forceinline__ void do_transpose(const void* __restrict__ in,
                                             ushort* __restrict__ out,
                                             int bx, int by, int in_rs, int out_rs,
                                             bool ib, ushort* tile /*32x33*/) {
    const int tx = threadIdx.x & 31, ty = threadIdx.x >> 5;
    #pragma unroll
    for (int rr = 0; rr < 32; rr += 8) {
        size_t idx = (size_t)(by * 32 + ty + rr) * in_rs + bx * 32 + tx;
        float v = ib ? bf2f(((const ushort*)in)[idx]) : ((const float*)in)[idx];
        tile[(ty + rr) * 33 + tx] = f2bf(scrub(v, 1e8f));
    }
    __syncthreads();
    #pragma unroll
    for (int rr = 0; rr < 32; rr += 8) {
        int r = bx * 32 + ty + rr;
        int c = by * 32 + tx;
        out[(size_t)r * out_rs + c] = tile[tx * 33 + (ty + rr)];
    }
}

// ---------------------------------------------------------------------------
// prep: fused LN1 (blocks 0..8191) + Wq^T (8192..8703) + Wkv^T (8704..8831).
// ---------------------------------------------------------------------------
__global__ __launch_bounds__(256) void prep_kernel(const void* __restrict__ xin,
                                                   const void* __restrict__ gin,
                                                   const void* __restrict__ Wq,
                                                   const void* __restrict__ Wkv,
                                                   ushort* __restrict__ xn,
                                                   ushort* __restrict__ wcatT,
                                                   const ushort* __restrict__ probe) {
    const bool ib = detect_bf16(probe);
    const int id = blockIdx.x;
    __shared__ ushort tile[32 * 33];
    __shared__ float red[8];

    if (id >= 8192) {
        if (id < 8704) {
            int t = id - 8192;                  // Wq[1024][512] -> wcatT[0:512)[1024]
            do_transpose(Wq, wcatT, t & 15, t >> 4, 512, 1024, ib, tile);
        } else {
            int t = id - 8704;                  // Wkv[1024][128] -> wcatT[512:640)[1024]
            do_transpose(Wkv, wcatT + (size_t)512 * 1024, t & 3, t >> 2, 128, 1024, ib, tile);
        }
        return;
    }

    const int row = id;
    const int tid = threadIdx.x;
    float v0, v1, v2, v3, g0, g1, g2, g3;
    if (ib) {
        uint2 u = *(const uint2*)((const ushort*)xin + (size_t)row * 1024 + tid * 4);
        v0 = bf2f((ushort)(u.x & 0xFFFF)); v1 = bf2f((ushort)(u.x >> 16));
        v2 = bf2f((ushort)(u.y & 0xFFFF)); v3 = bf2f((ushort)(u.y >> 16));
        uint2 gu = *(const uint2*)((const ushort*)gin + tid * 4);
        g0 = bf2f((ushort)(gu.x & 0xFFFF)); g1 = bf2f((ushort)(gu.x >> 16));
        g2 = bf2f((ushort)(gu.y & 0xFFFF)); g3 = bf2f((ushort)(gu.y >> 16));
    } else {
        float4 xv = *(const float4*)((const float*)xin + (size_t)row * 1024 + tid * 4);
        v0 = xv.x; v1 = xv.y; v2 = xv.z; v3 = xv.w;
        float4 gv = *(const float4*)((const float*)gin + tid * 4);
        g0 = gv.x; g1 = gv.y; g2 = gv.z; g3 = gv.w;
    }
    v0 = scrub(v0, 1e8f); v1 = scrub(v1, 1e8f); v2 = scrub(v2, 1e8f); v3 = scrub(v3, 1e8f);
    g0 = scrub(g0, 1e8f); g1 = scrub(g1, 1e8f); g2 = scrub(g2, 1e8f); g3 = scrub(g3, 1e8f);

    float s  = v0 + v1 + v2 + v3;
    float sq = v0 * v0 + v1 * v1 + v2 * v2 + v3 * v3;
    #pragma unroll
    for (int off = 1; off < 64; off <<= 1) {
        s  += __shfl_xor(s, off);
        sq += __shfl_xor(sq, off);
    }
    const int w = tid >> 6, lane = tid & 63;
    if (lane == 0) { red[w] = s; red[w + 4] = sq; }
    __syncthreads();
    float S  = red[0] + red[1] + red[2] + red[3];
    float SQ = red[4] + red[5] + red[6] + red[7];

    float mean = S * (1.0f / 1024.0f);
    float var  = SQ * (1.0f / 1024.0f) - mean * mean;
    float rstd = rsqrtf(fmaxf(var, 0.0f) + 1e-5f);

    uint2 ov;
    ov.x = pk2((v0 - mean) * rstd * g0, (v1 - mean) * rstd * g1);
    ov.y = pk2((v2 - mean) * rstd * g2, (v3 - mean) * rstd * g3);
    *(uint2*)(xn + (size_t)row * 1024 + tid * 4) = ov;
}

// ---------------------------------------------------------------------------
// Standalone Wout transpose (r6-proven position: after gemm_qkv, xn dead).
// ---------------------------------------------------------------------------
__global__ __launch_bounds__(256) void wout_tr_kernel(const void* __restrict__ Wout,
                                                      ushort* __restrict__ woT,
                                                      const ushort* __restrict__ probe) {
    const bool ib = detect_bf16(probe);
    __shared__ ushort tile[32 * 33];
    do_transpose(Wout, woT, blockIdx.x, blockIdx.y, 1024, 512, ib, tile);
}

// ---------------------------------------------------------------------------
// LN2: input bf16, gamma + OUTPUT dtype detected.
// ---------------------------------------------------------------------------
__global__ __launch_bounds__(256) void ln2_kernel(const ushort* __restrict__ y,
                                                  const void* __restrict__ gin,
                                                  void* __restrict__ out,
                                                  const ushort* __restrict__ probe) {
    const bool ob = detect_bf16(probe);
    const int row = blockIdx.x;
    const int tid = threadIdx.x;

    uint2 u = *(const uint2*)(y + (size_t)row * 1024 + tid * 4);
    float v0 = scrub(bf2f((ushort)(u.x & 0xFFFF)), 1e8f);
    float v1 = scrub(bf2f((ushort)(u.x >> 16)),    1e8f);
    float v2 = scrub(bf2f((ushort)(u.y & 0xFFFF)), 1e8f);
    float v3 = scrub(bf2f((ushort)(u.y >> 16)),    1e8f);

    float g0, g1, g2, g3;
    if (ob) {
        uint2 gu = *(const uint2*)((const ushort*)gin + tid * 4);
        g0 = bf2f((ushort)(gu.x & 0xFFFF)); g1 = bf2f((ushort)(gu.x >> 16));
        g2 = bf2f((ushort)(gu.y & 0xFFFF)); g3 = bf2f((ushort)(gu.y >> 16));
    } else {
        float4 gv = *(const float4*)((const float*)gin + tid * 4);
        g0 = gv.x; g1 = gv.y; g2 = gv.z; g3 = gv.w;
    }
    g0 = scrub(g0, 1e8f); g1 = scrub(g1, 1e8f); g2 = scrub(g2, 1e8f); g3 = scrub(g3, 1e8f);

    float s  = v0 + v1 + v2 + v3;
    float sq = v0 * v0 + v1 * v1 + v2 * v2 + v3 * v3;
    #pragma unroll
    for (int off = 1; off < 64; off <<= 1) {
        s  += __shfl_xor(s, off);
        sq += __shfl_xor(sq, off);
    }
    __shared__ float red[8];
    const int w = tid >> 6, lane = tid & 63;
    if (lane == 0) { red[w] = s; red[w + 4] = sq; }
    __syncthreads();
    float S  = red[0] + red[1] + red[2] + red[3];
    float SQ = red[4] + red[5] + red[6] + red[7];

    float mean = S * (1.0f / 1024.0f);
    float var  = SQ * (1.0f / 1024.0f) - mean * mean;
    float rstd = rsqrtf(fmaxf(var, 0.0f) + 1e-5f);

    float o0 = (v0 - mean) * rstd * g0;
    float o1 = (v1 - mean) * rstd * g1;
    float o2 = (v2 - mean) * rstd * g2;
    float o3 = (v3 - mean) * rstd * g3;
    if (ob) {
        uint2 ov;
        ov.x = pk2(o0, o1);
        ov.y = pk2(o2, o3);
        *(uint2*)((ushort*)out + (size_t)row * 1024 + tid * 4) = ov;
    } else {
        *(float4*)((float*)out + (size_t)row * 1024 + tid * 4) = make_float4(o0, o1, o2, o3);
    }
}

// ---------------------------------------------------------------------------
// Fused QKV GEMM with global_load_lds staging.
// grid (10,128): bx<8 q (l2norm, pre-scaled by log2(e) for exp2 softmax),
// bx==8 k (l2norm), bx==9 v (-> V^T).
// ---------------------------------------------------------------------------
__global__ __launch_bounds__(256) void gemm_qkv(const ushort* __restrict__ A,
                                                const ushort* __restrict__ Bt,
                                                ushort* __restrict__ qb,
                                                ushort* __restrict__ kb,
                                                ushort* __restrict__ vt) {
    __shared__ ushort a_t[64 * 32];
    __shared__ ushort b_t[64 * 32];

    const int bx = blockIdx.x;
    const int n0 = bx * 64, m0 = blockIdx.y * 64;
    const int tid = threadIdx.x;
    const int w = tid >> 6, lane = tid & 63;
    const int fm = lane & 15, quad = lane >> 4;
    const int K = 1024;

    // glds chunk map: thread t -> row t>>2 (0..63), k-octet t&3
    const ushort* ag = A + (size_t)(m0 + (tid >> 2)) * K + (tid & 3) * 8;
    const ushort* bg = Bt + (size_t)(n0 + (tid >> 2)) * K + (tid & 3) * 8;
    ushort* la = a_t + w * 512;   // wave-uniform LDS base
    ushort* lb = b_t + w * 512;

    floatx4 acc[4];
    floatx4 zero4 = {0.0f, 0.0f, 0.0f, 0.0f};
    #pragma unroll
    for (int nt = 0; nt < 4; nt++) acc[nt] = zero4;

    union U8 { uint4 u4; short8 s8; };

    for (int k0 = 0; k0 < K; k0 += 32) {
        __syncthreads();                   // prior iter's frag reads done
        glds16(ag + k0, la);
        glds16(bg + k0, lb);
        __syncthreads();                   // vmcnt drained before reads

        U8 af;
        af.u4 = *(const uint4*)&a_t[(w * 16 + fm) * 32 + quad * 8];
        #pragma unroll
        for (int nt = 0; nt < 4; nt++) {
            U8 bf;
            bf.u4 = *(const uint4*)&b_t[(nt * 16 + fm) * 32 + quad * 8];
            acc[nt] = __builtin_amdgcn_mfma_f32_16x16x32_bf16(af.s8, bf.s8, acc[nt], 0, 0, 0);
        }
    }

    if (bx < 9) {
        // q gets 4*log2(e) so attn's QK accumulates S*log2e -> bare exp2.
        const float qsc = (bx < 8) ? 5.7707801636f : 4.0f;
        float sc[4];
        #pragma unroll
        for (int r = 0; r < 4; r++) {
            float ss = acc[0][r] * acc[0][r] + acc[1][r] * acc[1][r]
                     + acc[2][r] * acc[2][r] + acc[3][r] * acc[3][r];
            ss += __shfl_xor(ss, 1);
            ss += __shfl_xor(ss, 2);
            ss += __shfl_xor(ss, 4);
            ss += __shfl_xor(ss, 8);
            sc[r] = qsc / fmaxf(sqrtf(ss), 1e-12f);
        }
        ushort* op;
        int rs;
        if (bx < 8) { op = qb + n0; rs = 512; }
        else        { op = kb;      rs = 64;  }
        #pragma unroll
        for (int nt = 0; nt < 4; nt++)
            #pragma unroll
            for (int r = 0; r < 4; r++)
                op[(size_t)(m0 + w * 16 + quad * 4 + r) * rs + nt * 16 + fm] =
                    f2bf(acc[nt][r] * sc[r]);
    } else {
        const int b = m0 >> 11;
        const int jb = (m0 & 2047) + w * 16 + quad * 4;
        ushort* vb = vt + (size_t)b * 64 * 2048 + jb;
        #pragma unroll
        for (int nt = 0; nt < 4; nt++) {
            uint2 pv;
            pv.x = pk2(acc[nt][0], acc[nt][1]);
            pv.y = pk2(acc[nt][2], acc[nt][3]);
            *(uint2*)(vb + (size_t)(nt * 16 + fm) * 2048) = pv;
        }
    }
}

// ---------------------------------------------------------------------------
// Out-projection GEMM, m97-style: 128x128 tile, BK=32, global_load_lds w=16.
// ---------------------------------------------------------------------------
__global__ __launch_bounds__(256) void gemm_bt128(const ushort* __restrict__ A,
                                                  const ushort* __restrict__ Bt,
                                                  ushort* __restrict__ C,
                                                  int M, int N, int K) {
    __shared__ ushort a_t[128][32];
    __shared__ ushort b_t[128][32];

    const int n0 = blockIdx.x * 128, m0 = blockIdx.y * 128;
    const int tid = threadIdx.x;
    const int w = tid >> 6, lane = tid & 63;
    const int fm = lane & 15, quad = lane >> 4;

    const int c0 = tid, c1 = tid + 256;
    const ushort* ag0 = A + (size_t)(m0 + (c0 >> 2)) * K + (c0 & 3) * 8;
    const ushort* ag1 = A + (size_t)(m0 + (c1 >> 2)) * K + (c1 & 3) * 8;
    const ushort* bg0 = Bt + (size_t)(n0 + (c0 >> 2)) * K + (c0 & 3) * 8;
    const ushort* bg1 = Bt + (size_t)(n0 + (c1 >> 2)) * K + (c1 & 3) * 8;
    ushort* la0 = &a_t[0][0] + w * 512;
    ushort* la1 = &a_t[0][0] + 2048 + w * 512;
    ushort* lb0 = &b_t[0][0] + w * 512;
    ushort* lb1 = &b_t[0][0] + 2048 + w * 512;

    floatx4 acc[2][8];
    floatx4 zero4 = {0.0f, 0.0f, 0.0f, 0.0f};
    #pragma unroll
    for (int mt = 0; mt < 2; mt++)
        #pragma unroll
        for (int nt = 0; nt < 8; nt++) acc[mt][nt] = zero4;

    union U8 { uint4 u4; short8 s8; };

    for (int k0 = 0; k0 < K; k0 += 32) {
        __syncthreads();
        glds16(ag0 + k0, la0);
        glds16(ag1 + k0, la1);
        glds16(bg0 + k0, lb0);
        glds16(bg1 + k0, lb1);
        __syncthreads();

        U8 af[2];
        #pragma unroll
        for (int mt = 0; mt < 2; mt++)
            af[mt].u4 = *(const uint4*)&a_t[w * 32 + mt * 16 + fm][quad * 8];
        #pragma unroll
        for (int nt = 0; nt < 8; nt++) {
            U8 bf;
            bf.u4 = *(const uint4*)&b_t[nt * 16 + fm][quad * 8];
            acc[0][nt] = __builtin_amdgcn_mfma_f32_16x16x32_bf16(af[0].s8, bf.s8, acc[0][nt], 0, 0, 0);
            acc[1][nt] = __builtin_amdgcn_mfma_f32_16x16x32_bf16(af[1].s8, bf.s8, acc[1][nt], 0, 0, 0);
        }
    }

    #pragma unroll
    for (int mt = 0; mt < 2; mt++)
        #pragma unroll
        for (int nt = 0; nt < 8; nt++)
            #pragma unroll
            for (int r = 0; r < 4; r++)
                C[(size_t)(m0 + w * 32 + mt * 16 + quad * 4 + r) * N + n0 + nt * 16 + fm] =
                    f2bf(acc[mt][nt][r]);
}

// ---------------------------------------------------------------------------
// Flash attention v4: 32x32x16 MFMA, octet-major LDS slabs, in-block split-K.
//
// r3 post-mortem: (a) occupancy was GRID-limited at 8 waves/CU (2048 waves
// chip-wide at 32 q/wave); (b) every b128 frag read paid exactly 4 extra
// bank cycles (4.19M = 4 * 2^20 reads) in the [row][d-octet^sw] layout.
//
// Fixes:
// (a) In-block key-split: 4 waves = 2 q-groups x 2 key-halves; grid (32,8,4)
//     = 1024 blocks -> 16 waves/CU. Partials (O^T + lsum) summed once via
//     LDS (this softmax has no running max -> split-K is a plain sum).
// (b) Octet-major LDS slabs: K stored as [d-octet][position] (slab = 1KB
//     contiguous), V^T as [key-octet][d]. Every frag read is 16 consecutive
//     lanes x 16B = 256B CONTIGUOUS runs -> conflict-free under any bank
//     model (same property as the DMA writes). No XOR swizzle at all.
//     Each slab = exactly one glds16 (64 lanes x 16B); the in-register-P
//     key permutation (bitswap bits 2,3) moves into the per-lane global
//     SOURCE address of the K staging.
//
// Steps of 32 keys (one 32x32 C-tile per step): per wave-step 4 QK MFMA +
// 4 PV MFMA, 8 contiguous b128 frag reads, 4 glds16. exp2 path: Q carries
// log2(e), C init = -16*log2(e), bare v_exp_f32.
// LDS: 2 ks x 2 buf x (4KB K + 4KB V) = 32KB -> 4 blocks/CU.
// ---------------------------------------------------------------------------
__global__ __launch_bounds__(256, 4) void attn_kernel(const ushort* __restrict__ q,
                                                      const ushort* __restrict__ kb,
                                                      const ushort* __restrict__ vt,
                                                      ushort* __restrict__ out) {
    __shared__ ushort smem[16384];          // 32 KB
    ushort* k_t = smem;                     // [ks][buf][oct8][pos32][8]: ks*4096+buf*2048+oct*256+pos*8
    ushort* v_t = smem + 8192;              // [ks][buf][oct4][d64][8] : ks*4096+buf*2048+oct*512+d*8

    const int i0 = blockIdx.x * 64;
    const int h0 = blockIdx.y, b = blockIdx.z;
    const int tid = threadIdx.x, w = tid >> 6, lane = tid & 63;
    const int qg = w & 1;          // query group of 32
    const int ks = w >> 1;         // key half: 0 -> [0,1024), 1 -> [1024,2048)
    const int cq = lane & 31;      // C col = query; A row = position / d
    const int hi = lane >> 5;      // k-slice half within fragment

    union U8 { uint4 u4; short8 s8; };

    // Q B-frags: qf[dm] holds Q[q=cq][d = 16*dm + 8*hi + j]
    const ushort* qbase = q + (size_t)(b * 2048 + i0 + qg * 32 + cq) * 512 + h0 * 64 + hi * 8;
    U8 qf[4];
    #pragma unroll
    for (int dm = 0; dm < 4; dm++) qf[dm].u4 = *(const uint4*)(qbase + dm * 16);

    floatx16 acc0, acc1;           // O^T partials: d 0..31 (acc0), 32..63 (acc1)
    #pragma unroll
    for (int i = 0; i < 16; i++) { acc0[i] = 0.0f; acc1[i] = 0.0f; }
    float lsum = 0.0f;

    const ushort* kbb = kb + (size_t)b * 2048 * 64;
    const ushort* vtb = vt + (size_t)b * 64 * 2048;

    // Staging sources (per-lane). K slab-pair c (octs 2c,2c+1): lane i supplies
    // K[key = ks*1024 + s*32 + perm(i&31)][d-octet 2c + (i>>5)]; perm = bitswap
    // bits 2,3 (in-register-P permutation). V slab oct o: lane i supplies
    // V^T[d = i][key-octet o of the step].
    const int p5 = (cq & ~12) | ((cq & 4) << 1) | ((cq & 8) >> 1);
    const ushort* kSrc = kbb + (size_t)(ks * 1024 + p5) * 64 + hi * 8;
    const ushort* vSrc = vtb + (size_t)lane * 2048 + ks * 1024;

    ushort* kT = k_t + ks * 4096;
    ushort* vT = v_t + ks * 4096;

    auto stage = [&](int s, int buf) {
        const int bo = buf * 2048;
        #pragma unroll
        for (int c = 2 * qg; c < 2 * qg + 2; c++) {
            glds16(kSrc + s * 2048 + c * 16, kT + bo + c * 512);
            glds16(vSrc + s * 32 + c * 8,  vT + bo + c * 512);
        }
    };

    auto compute = [&](int buf) {
        const int bo = buf * 2048;
        // QK^T (positions 0..31 of this step, key-permuted)
        floatx16 st;
        #pragma unroll
        for (int i = 0; i < 16; i++) st[i] = -23.0831206f;   // -16*log2(e)
        #pragma unroll
        for (int dm = 0; dm < 4; dm++) {
            U8 kf;
            kf.u4 = *(const uint4*)&kT[bo + (2 * dm + hi) * 256 + cq * 8];
            st = __builtin_amdgcn_mfma_f32_32x32x16_bf16(kf.s8, qf[dm].s8, st, 0, 0, 0);
        }
        float p_[16];
        #pragma unroll
        for (int r = 0; r < 16; r++) p_[r] = __builtin_amdgcn_exp2f(st[r]);
        lsum += (((p_[0] + p_[1]) + (p_[2] + p_[3])) + ((p_[4] + p_[5]) + (p_[6] + p_[7])))
              + (((p_[8] + p_[9]) + (p_[10] + p_[11])) + ((p_[12] + p_[13]) + (p_[14] + p_[15])));
        U8 pb0, pb1;               // PV B-frags: regs 0-7 -> k-slice 0, 8-15 -> slice 1
        pb0.u4.x = pk2(p_[0], p_[1]);   pb0.u4.y = pk2(p_[2], p_[3]);
        pb0.u4.z = pk2(p_[4], p_[5]);   pb0.u4.w = pk2(p_[6], p_[7]);
        pb1.u4.x = pk2(p_[8], p_[9]);   pb1.u4.y = pk2(p_[10], p_[11]);
        pb1.u4.z = pk2(p_[12], p_[13]); pb1.u4.w = pk2(p_[14], p_[15]);
        // PV: O^T(d-tile) += V^T(key-slice) x P^T
        U8 vf;
        vf.u4 = *(const uint4*)&vT[bo + (0 + hi) * 512 + cq * 8];
        acc0 = __builtin_amdgcn_mfma_f32_32x32x16_bf16(vf.s8, pb0.s8, acc0, 0, 0, 0);
        vf.u4 = *(const uint4*)&vT[bo + (2 + hi) * 512 + cq * 8];
        acc0 = __builtin_amdgcn_mfma_f32_32x32x16_bf16(vf.s8, pb1.s8, acc0, 0, 0, 0);
        vf.u4 = *(const uint4*)&vT[bo + (0 + hi) * 512 + (32 + cq) * 8];
        acc1 = __builtin_amdgcn_mfma_f32_32x32x16_bf16(vf.s8, pb0.s8, acc1, 0, 0, 0);
        vf.u4 = *(const uint4*)&vT[bo + (2 + hi) * 512 + (32 + cq) * 8];
        acc1 = __builtin_amdgcn_mfma_f32_32x32x16_bf16(vf.s8, pb1.s8, acc1, 0, 0, 0);
    };

    // prologue: stage step 0 into buf0
    stage(0, 0);
    __syncthreads();

    for (int s = 0; s < 32; s++) {
        const int cur = s & 1;
        if (s < 31) stage(s + 1, cur ^ 1);
        compute(cur);
        __syncthreads();                    // drains next-buf staging; WAR on cur
    }

    // ---- split-K combine via LDS (stride-36 f32: 16B-aligned, 2-way = free) ----
    float* row = (float*)smem + (qg * 64 + lane) * 36;
    if (ks == 1) {
        #pragma unroll
        for (int i = 0; i < 16; i++) { row[i] = acc0[i]; row[16 + i] = acc1[i]; }
        row[32] = lsum;
    }
    __syncthreads();
    if (ks == 1) return;
    #pragma unroll
    for (int i = 0; i < 16; i++) { acc0[i] += row[i]; acc1[i] += row[16 + i]; }
    lsum += row[32];
    lsum += __shfl_xor(lsum, 32);           // combine hi/lo position halves
    float li = 1.0f / fmaxf(lsum, 1e-30f);

    // write out: reg 4t+u of acc0 -> d = u + 8t + 4hi; acc1 -> +32
    ushort* ob = out + (size_t)(b * 2048 + i0 + qg * 32 + cq) * 512 + h0 * 64 + hi * 4;
    #pragma unroll
    for (int t = 0; t < 4; t++) {
        uint2 ov;
        ov.x = pk2(acc0[4 * t] * li, acc0[4 * t + 1] * li);
        ov.y = pk2(acc0[4 * t + 2] * li, acc0[4 * t + 3] * li);
        *(uint2*)(ob + t * 8) = ov;
        ov.x = pk2(acc1[4 * t] * li, acc1[4 * t + 1] * li);
        ov.y = pk2(acc1[4 * t + 2] * li, acc1[4 * t + 3] * li);
        *(uint2*)(ob + 32 + t * 8) = ov;
    }
}

// ---------------------------------------------------------------------------
// Memory plan (bf16 intermediates, ws_size needed = 16MB):
//   d_out: xn [0:16MB) (dead after gemm_qkv) -> ao [0:8MB), woT [8:16MB)
//   ws:    qb [0:8), kb [8:9), vt [9:11), wcatT [11:12.25); y [0:16) after attn.
// Dispatches (6): prep, gemm_qkv, wout_tr, attn, gemm_bt128, ln2.
// ---------------------------------------------------------------------------
extern "C" void kernel_launch(void* const* d_in, const int* in_sizes, int n_in,
                              void* d_out, int out_size, void* d_ws, size_t ws_size,
                              hipStream_t stream) {
    const void* x          = d_in[0];
    const void* norm_g     = d_in[1];
    const void* Wq         = d_in[2];
    const void* Wkv        = d_in[3];
    const void* Wout       = d_in[4];
    const void* out_norm_g = d_in[5];
    const ushort* probe = (const ushort*)d_in[0];
    ushort* ws = (ushort*)d_ws;

    const size_t M1 = 1024 * 1024 / 2;  // bf16 elems per MB
    ushort* xn    = (ushort*)d_out;
    ushort* ao    = (ushort*)d_out;
    ushort* woT   = (ushort*)((char*)d_out + (8u << 20));
    ushort* qb    = ws;
    ushort* kb    = ws + 8 * M1;
    ushort* vt    = ws + 9 * M1;
    ushort* wcatT = ws + 11 * M1;
    ushort* y     = ws;

    // prep: LN1 + Wq^T + Wkv^T fused
    prep_kernel<<<8832, 256, 0, stream>>>(x, norm_g, Wq, Wkv, xn, wcatT, probe);

    // fused q/k/v projection + l2norm + V^T
    gemm_qkv<<<dim3(10, 128), 256, 0, stream>>>(xn, wcatT, qb, kb, vt);

    // Wout^T -> d_out[8:16MB) (xn dead now)
    wout_tr_kernel<<<dim3(32, 16), 256, 0, stream>>>(Wout, woT, probe);

    // attention -> ao
    attn_kernel<<<dim3(32, 8, 4), 256, 0, stream>>>(qb, kb, vt, ao);

    // y = ao @ Wout  (128-tile, global_load_lds)
    gemm_bt128<<<dim3(8, 64), 256, 0, stream>>>(ao, woT, y, 8192, 1024, 512);

    // LN2: y -> final output
    ln2_kernel<<<8192, 256, 0, stream>>>(y, out_norm_g, d_out, probe);
}

// Round 5
// 207.697 us; speedup vs baseline: 1.0929x; 1.0929x over previous
//
#include <hip/hip_runtime.h>
#include <hip/hip_bf16.h>

typedef __attribute__((ext_vector_type(8))) short short8;
typedef __attribute__((ext_vector_type(4))) float floatx4;
typedef __attribute__((ext_vector_type(16))) float floatx16;

__device__ __forceinline__ float bf2f(ushort u) {
    return __uint_as_float(((unsigned int)u) << 16);
}
__device__ __forceinline__ ushort f2bf(float f) {
    unsigned int u = __float_as_uint(f);
    unsigned int r = (u + 0x7FFFu + ((u >> 16) & 1u)) >> 16;
    return (ushort)r;
}
// packed f32x2 -> bf16x2
__device__ __forceinline__ unsigned int pk2(float a, float b) {
    union { __hip_bfloat162 h; unsigned int u; } cv;
    cv.h = __float22bfloat162_rn(make_float2(a, b));
    return cv.u;
}
__device__ __forceinline__ float scrub(float v, float lim) {
    return fminf(fmaxf(v, -lim), lim);
}
// async global->LDS, 16B per lane (lane i lands at wave-uniform lds base + 16*i)
__device__ __forceinline__ void glds16(const ushort* g, ushort* l) {
    __builtin_amdgcn_global_load_lds((const __attribute__((address_space(1))) void*)g,
                                     (__attribute__((address_space(3))) void*)l, 16, 0, 0);
}

// Wave-uniform dtype probe on x: bf16 N(0,1) data has exponent byte in [117,131]
// ~99% at even ushort indices; fp32-as-ushort gives ~6%. 32 samples, thr 16.
__device__ __forceinline__ bool detect_bf16(const ushort* __restrict__ probe) {
    const int lane = threadIdx.x & 63;
    ushort u = probe[(lane & 31) * 2];
    int e = (u >> 7) & 0xFF;
    bool pl = (e >= 117) && (e <= 131) && (lane < 32);
    return __popcll(__ballot(pl)) >= 16;
}

// ---------------------------------------------------------------------------
// Transpose helper (256 threads).
// ---------------------------------------------------------------------------
__device__ __forceinline__ void do_transpose(const void* __restrict__ in,
                                             ushort* __restrict__ out,
                                             int bx, int by, int in_rs, int out_rs,
                                             bool ib, ushort* tile /*32x33*/) {
    const int tx = threadIdx.x & 31, ty = threadIdx.x >> 5;
    #pragma unroll
    for (int rr = 0; rr < 32; rr += 8) {
        size_t idx = (size_t)(by * 32 + ty + rr) * in_rs + bx * 32 + tx;
        float v = ib ? bf2f(((const ushort*)in)[idx]) : ((const float*)in)[idx];
        tile[(ty + rr) * 33 + tx] = f2bf(scrub(v, 1e8f));
    }
    __syncthreads();
    #pragma unroll
    for (int rr = 0; rr < 32; rr += 8) {
        int r = bx * 32 + ty + rr;
        int c = by * 32 + tx;
        out[(size_t)r * out_rs + c] = tile[tx * 33 + (ty + rr)];
    }
}

// ---------------------------------------------------------------------------
// prep: fused LN1 (blocks 0..8191) + Wq^T (8192..8703) + Wkv^T (8704..8831).
// ---------------------------------------------------------------------------
__global__ __launch_bounds__(256) void prep_kernel(const void* __restrict__ xin,
                                                   const void* __restrict__ gin,
                                                   const void* __restrict__ Wq,
                                                   const void* __restrict__ Wkv,
                                                   ushort* __restrict__ xn,
                                                   ushort* __restrict__ wcatT,
                                                   const ushort* __restrict__ probe) {
    const bool ib = detect_bf16(probe);
    const int id = blockIdx.x;
    __shared__ ushort tile[32 * 33];
    __shared__ float red[8];

    if (id >= 8192) {
        if (id < 8704) {
            int t = id - 8192;                  // Wq[1024][512] -> wcatT[0:512)[1024]
            do_transpose(Wq, wcatT, t & 15, t >> 4, 512, 1024, ib, tile);
        } else {
            int t = id - 8704;                  // Wkv[1024][128] -> wcatT[512:640)[1024]
            do_transpose(Wkv, wcatT + (size_t)512 * 1024, t & 3, t >> 2, 128, 1024, ib, tile);
        }
        return;
    }

    const int row = id;
    const int tid = threadIdx.x;
    float v0, v1, v2, v3, g0, g1, g2, g3;
    if (ib) {
        uint2 u = *(const uint2*)((const ushort*)xin + (size_t)row * 1024 + tid * 4);
        v0 = bf2f((ushort)(u.x & 0xFFFF)); v1 = bf2f((ushort)(u.x >> 16));
        v2 = bf2f((ushort)(u.y & 0xFFFF)); v3 = bf2f((ushort)(u.y >> 16));
        uint2 gu = *(const uint2*)((const ushort*)gin + tid * 4);
        g0 = bf2f((ushort)(gu.x & 0xFFFF)); g1 = bf2f((ushort)(gu.x >> 16));
        g2 = bf2f((ushort)(gu.y & 0xFFFF)); g3 = bf2f((ushort)(gu.y >> 16));
    } else {
        float4 xv = *(const float4*)((const float*)xin + (size_t)row * 1024 + tid * 4);
        v0 = xv.x; v1 = xv.y; v2 = xv.z; v3 = xv.w;
        float4 gv = *(const float4*)((const float*)gin + tid * 4);
        g0 = gv.x; g1 = gv.y; g2 = gv.z; g3 = gv.w;
    }
    v0 = scrub(v0, 1e8f); v1 = scrub(v1, 1e8f); v2 = scrub(v2, 1e8f); v3 = scrub(v3, 1e8f);
    g0 = scrub(g0, 1e8f); g1 = scrub(g1, 1e8f); g2 = scrub(g2, 1e8f); g3 = scrub(g3, 1e8f);

    float s  = v0 + v1 + v2 + v3;
    float sq = v0 * v0 + v1 * v1 + v2 * v2 + v3 * v3;
    #pragma unroll
    for (int off = 1; off < 64; off <<= 1) {
        s  += __shfl_xor(s, off);
        sq += __shfl_xor(sq, off);
    }
    const int w = tid >> 6, lane = tid & 63;
    if (lane == 0) { red[w] = s; red[w + 4] = sq; }
    __syncthreads();
    float S  = red[0] + red[1] + red[2] + red[3];
    float SQ = red[4] + red[5] + red[6] + red[7];

    float mean = S * (1.0f / 1024.0f);
    float var  = SQ * (1.0f / 1024.0f) - mean * mean;
    float rstd = rsqrtf(fmaxf(var, 0.0f) + 1e-5f);

    uint2 ov;
    ov.x = pk2((v0 - mean) * rstd * g0, (v1 - mean) * rstd * g1);
    ov.y = pk2((v2 - mean) * rstd * g2, (v3 - mean) * rstd * g3);
    *(uint2*)(xn + (size_t)row * 1024 + tid * 4) = ov;
}

// ---------------------------------------------------------------------------
// Standalone Wout transpose (r6-proven position: after gemm_qkv, xn dead).
// ---------------------------------------------------------------------------
__global__ __launch_bounds__(256) void wout_tr_kernel(const void* __restrict__ Wout,
                                                      ushort* __restrict__ woT,
                                                      const ushort* __restrict__ probe) {
    const bool ib = detect_bf16(probe);
    __shared__ ushort tile[32 * 33];
    do_transpose(Wout, woT, blockIdx.x, blockIdx.y, 1024, 512, ib, tile);
}

// ---------------------------------------------------------------------------
// LN2: input bf16, gamma + OUTPUT dtype detected.
// ---------------------------------------------------------------------------
__global__ __launch_bounds__(256) void ln2_kernel(const ushort* __restrict__ y,
                                                  const void* __restrict__ gin,
                                                  void* __restrict__ out,
                                                  const ushort* __restrict__ probe) {
    const bool ob = detect_bf16(probe);
    const int row = blockIdx.x;
    const int tid = threadIdx.x;

    uint2 u = *(const uint2*)(y + (size_t)row * 1024 + tid * 4);
    float v0 = scrub(bf2f((ushort)(u.x & 0xFFFF)), 1e8f);
    float v1 = scrub(bf2f((ushort)(u.x >> 16)),    1e8f);
    float v2 = scrub(bf2f((ushort)(u.y & 0xFFFF)), 1e8f);
    float v3 = scrub(bf2f((ushort)(u.y >> 16)),    1e8f);

    float g0, g1, g2, g3;
    if (ob) {
        uint2 gu = *(const uint2*)((const ushort*)gin + tid * 4);
        g0 = bf2f((ushort)(gu.x & 0xFFFF)); g1 = bf2f((ushort)(gu.x >> 16));
        g2 = bf2f((ushort)(gu.y & 0xFFFF)); g3 = bf2f((ushort)(gu.y >> 16));
    } else {
        float4 gv = *(const float4*)((const float*)gin + tid * 4);
        g0 = gv.x; g1 = gv.y; g2 = gv.z; g3 = gv.w;
    }
    g0 = scrub(g0, 1e8f); g1 = scrub(g1, 1e8f); g2 = scrub(g2, 1e8f); g3 = scrub(g3, 1e8f);

    float s  = v0 + v1 + v2 + v3;
    float sq = v0 * v0 + v1 * v1 + v2 * v2 + v3 * v3;
    #pragma unroll
    for (int off = 1; off < 64; off <<= 1) {
        s  += __shfl_xor(s, off);
        sq += __shfl_xor(sq, off);
    }
    __shared__ float red[8];
    const int w = tid >> 6, lane = tid & 63;
    if (lane == 0) { red[w] = s; red[w + 4] = sq; }
    __syncthreads();
    float S  = red[0] + red[1] + red[2] + red[3];
    float SQ = red[4] + red[5] + red[6] + red[7];

    float mean = S * (1.0f / 1024.0f);
    float var  = SQ * (1.0f / 1024.0f) - mean * mean;
    float rstd = rsqrtf(fmaxf(var, 0.0f) + 1e-5f);

    float o0 = (v0 - mean) * rstd * g0;
    float o1 = (v1 - mean) * rstd * g1;
    float o2 = (v2 - mean) * rstd * g2;
    float o3 = (v3 - mean) * rstd * g3;
    if (ob) {
        uint2 ov;
        ov.x = pk2(o0, o1);
        ov.y = pk2(o2, o3);
        *(uint2*)((ushort*)out + (size_t)row * 1024 + tid * 4) = ov;
    } else {
        *(float4*)((float*)out + (size_t)row * 1024 + tid * 4) = make_float4(o0, o1, o2, o3);
    }
}

// ---------------------------------------------------------------------------
// Fused QKV GEMM with global_load_lds staging.
// grid (10,128): bx<8 q (l2norm, pre-scaled by log2(e) for exp2 softmax),
// bx==8 k (l2norm -> SLAB layout), bx==9 v (-> SLAB layout).
//
// r4->r5: K/V are written directly in attn's LDS slab format so attn's
// global_load_lds staging reads are CONTIGUOUS 1KB chunks (r4's octet-major
// LDS layout forced a transpose-gather on the DMA source: 32-64 scattered
// segments per glds16 -> latency-bound, 81us).
//   K: kb[b][kblk32][d-oct8][pos32][e8], pos = bitswap23(key&31) (bakes the
//      in-register-P permutation into the layout).
//   V: vt[b][kblk32][k-oct4][d64][kk8].
// ---------------------------------------------------------------------------
__global__ __launch_bounds__(256) void gemm_qkv(const ushort* __restrict__ A,
                                                const ushort* __restrict__ Bt,
                                                ushort* __restrict__ qb,
                                                ushort* __restrict__ kb,
                                                ushort* __restrict__ vt) {
    __shared__ ushort a_t[64 * 32];
    __shared__ ushort b_t[64 * 32];

    const int bx = blockIdx.x;
    const int n0 = bx * 64, m0 = blockIdx.y * 64;
    const int tid = threadIdx.x;
    const int w = tid >> 6, lane = tid & 63;
    const int fm = lane & 15, quad = lane >> 4;
    const int K = 1024;

    // glds chunk map: thread t -> row t>>2 (0..63), k-octet t&3
    const ushort* ag = A + (size_t)(m0 + (tid >> 2)) * K + (tid & 3) * 8;
    const ushort* bg = Bt + (size_t)(n0 + (tid >> 2)) * K + (tid & 3) * 8;
    ushort* la = a_t + w * 512;   // wave-uniform LDS base
    ushort* lb = b_t + w * 512;

    floatx4 acc[4];
    floatx4 zero4 = {0.0f, 0.0f, 0.0f, 0.0f};
    #pragma unroll
    for (int nt = 0; nt < 4; nt++) acc[nt] = zero4;

    union U8 { uint4 u4; short8 s8; };

    for (int k0 = 0; k0 < K; k0 += 32) {
        __syncthreads();                   // prior iter's frag reads done
        glds16(ag + k0, la);
        glds16(bg + k0, lb);
        __syncthreads();                   // vmcnt drained before reads

        U8 af;
        af.u4 = *(const uint4*)&a_t[(w * 16 + fm) * 32 + quad * 8];
        #pragma unroll
        for (int nt = 0; nt < 4; nt++) {
            U8 bf;
            bf.u4 = *(const uint4*)&b_t[(nt * 16 + fm) * 32 + quad * 8];
            acc[nt] = __builtin_amdgcn_mfma_f32_16x16x32_bf16(af.s8, bf.s8, acc[nt], 0, 0, 0);
        }
    }

    if (bx < 9) {
        // q gets 4*log2(e) so attn's QK accumulates S*log2e -> bare exp2.
        const float qsc = (bx < 8) ? 5.7707801636f : 4.0f;
        float sc[4];
        #pragma unroll
        for (int r = 0; r < 4; r++) {
            float ss = acc[0][r] * acc[0][r] + acc[1][r] * acc[1][r]
                     + acc[2][r] * acc[2][r] + acc[3][r] * acc[3][r];
            ss += __shfl_xor(ss, 1);
            ss += __shfl_xor(ss, 2);
            ss += __shfl_xor(ss, 4);
            ss += __shfl_xor(ss, 8);
            sc[r] = qsc / fmaxf(sqrtf(ss), 1e-12f);
        }
        if (bx < 8) {
            ushort* op = qb + n0;
            #pragma unroll
            for (int nt = 0; nt < 4; nt++)
                #pragma unroll
                for (int r = 0; r < 4; r++)
                    op[(size_t)(m0 + w * 16 + quad * 4 + r) * 512 + nt * 16 + fm] =
                        f2bf(acc[nt][r] * sc[r]);
        } else {
            // K slab write: key = m0 + w*16 + quad*4 + r, d = nt*16 + fm.
            // idx = bb*131072 + kblk*2048 + (d>>3)*256 + bitswap23(key&31)*8 + (d&7)
            const int bb = m0 >> 11;
            const int kblk = ((m0 & 2047) >> 5) + (w >> 1);
            const int qsw = ((quad & 1) << 1) | (quad >> 1);   // bitswap23 of quad
            ushort* op = kb + (size_t)bb * 131072 + kblk * 2048
                       + (w & 1) * 128 + qsw * 32 + (fm & 7);
            #pragma unroll
            for (int nt = 0; nt < 4; nt++) {
                const int oct = nt * 2 + (fm >> 3);
                #pragma unroll
                for (int r = 0; r < 4; r++)
                    op[oct * 256 + r * 8] = f2bf(acc[nt][r] * sc[r]);
            }
        }
    } else {
        // V slab write: key = m0 + w*16 + quad*4 + r, d = nt*16 + fm.
        // idx = bb*131072 + kblk*2048 + ((key>>3)&3)*512 + d*8 + (key&7)
        const int bb = m0 >> 11;
        const int kblk = ((m0 & 2047) >> 5) + (w >> 1);
        const int koct = ((w & 1) * 2 + (quad >> 1)) & 3;
        ushort* vb = vt + (size_t)bb * 131072 + kblk * 2048 + koct * 512 + (quad & 1) * 4;
        #pragma unroll
        for (int nt = 0; nt < 4; nt++) {
            uint2 pv;
            pv.x = pk2(acc[nt][0], acc[nt][1]);
            pv.y = pk2(acc[nt][2], acc[nt][3]);
            *(uint2*)(vb + (nt * 16 + fm) * 8) = pv;
        }
    }
}

// ---------------------------------------------------------------------------
// Out-projection GEMM, m97-style: 128x128 tile, BK=32, global_load_lds w=16.
// ---------------------------------------------------------------------------
__global__ __launch_bounds__(256) void gemm_bt128(const ushort* __restrict__ A,
                                                  const ushort* __restrict__ Bt,
                                                  ushort* __restrict__ C,
                                                  int M, int N, int K) {
    __shared__ ushort a_t[128][32];
    __shared__ ushort b_t[128][32];

    const int n0 = blockIdx.x * 128, m0 = blockIdx.y * 128;
    const int tid = threadIdx.x;
    const int w = tid >> 6, lane = tid & 63;
    const int fm = lane & 15, quad = lane >> 4;

    const int c0 = tid, c1 = tid + 256;
    const ushort* ag0 = A + (size_t)(m0 + (c0 >> 2)) * K + (c0 & 3) * 8;
    const ushort* ag1 = A + (size_t)(m0 + (c1 >> 2)) * K + (c1 & 3) * 8;
    const ushort* bg0 = Bt + (size_t)(n0 + (c0 >> 2)) * K + (c0 & 3) * 8;
    const ushort* bg1 = Bt + (size_t)(n0 + (c1 >> 2)) * K + (c1 & 3) * 8;
    ushort* la0 = &a_t[0][0] + w * 512;
    ushort* la1 = &a_t[0][0] + 2048 + w * 512;
    ushort* lb0 = &b_t[0][0] + w * 512;
    ushort* lb1 = &b_t[0][0] + 2048 + w * 512;

    floatx4 acc[2][8];
    floatx4 zero4 = {0.0f, 0.0f, 0.0f, 0.0f};
    #pragma unroll
    for (int mt = 0; mt < 2; mt++)
        #pragma unroll
        for (int nt = 0; nt < 8; nt++) acc[mt][nt] = zero4;

    union U8 { uint4 u4; short8 s8; };

    for (int k0 = 0; k0 < K; k0 += 32) {
        __syncthreads();
        glds16(ag0 + k0, la0);
        glds16(ag1 + k0, la1);
        glds16(bg0 + k0, lb0);
        glds16(bg1 + k0, lb1);
        __syncthreads();

        U8 af[2];
        #pragma unroll
        for (int mt = 0; mt < 2; mt++)
            af[mt].u4 = *(const uint4*)&a_t[w * 32 + mt * 16 + fm][quad * 8];
        #pragma unroll
        for (int nt = 0; nt < 8; nt++) {
            U8 bf;
            bf.u4 = *(const uint4*)&b_t[nt * 16 + fm][quad * 8];
            acc[0][nt] = __builtin_amdgcn_mfma_f32_16x16x32_bf16(af[0].s8, bf.s8, acc[0][nt], 0, 0, 0);
            acc[1][nt] = __builtin_amdgcn_mfma_f32_16x16x32_bf16(af[1].s8, bf.s8, acc[1][nt], 0, 0, 0);
        }
    }

    #pragma unroll
    for (int mt = 0; mt < 2; mt++)
        #pragma unroll
        for (int nt = 0; nt < 8; nt++)
            #pragma unroll
            for (int r = 0; r < 4; r++)
                C[(size_t)(m0 + w * 32 + mt * 16 + quad * 4 + r) * N + n0 + nt * 16 + fm] =
                    f2bf(acc[mt][nt][r]);
}

// ---------------------------------------------------------------------------
// Flash attention v5: 32x32x16 MFMA, slab LDS layout (conflict-free reads,
// r4) + CONTIGUOUS slab staging (gemm_qkv pre-formats K/V) + in-block
// split-K for 16 waves/CU.
//
// Every glds16 is a contiguous 1KB global read landing in a contiguous 1KB
// LDS slab; every ds_read_b128 is a 16-lane 256B contiguous run. Compute
// identical to r4 (validated). Steps of 32 keys, double-buffered; per
// wave-step: 4 glds16, 8 b128 reads, 8 MFMA, 16 exp2.
// LDS: 2 ks x 2 buf x (4KB K + 4KB V) = 32KB -> 4 blocks/CU.
// ---------------------------------------------------------------------------
__global__ __launch_bounds__(256, 4) void attn_kernel(const ushort* __restrict__ q,
                                                      const ushort* __restrict__ kb,
                                                      const ushort* __restrict__ vt,
                                                      ushort* __restrict__ out) {
    __shared__ ushort smem[16384];          // 32 KB
    ushort* k_t = smem;                     // [ks][buf][oct8][pos32][8]
    ushort* v_t = smem + 8192;              // [ks][buf][oct4][d64][8]

    const int i0 = blockIdx.x * 64;
    const int h0 = blockIdx.y, b = blockIdx.z;
    const int tid = threadIdx.x, w = tid >> 6, lane = tid & 63;
    const int qg = w & 1;          // query group of 32
    const int ks = w >> 1;         // key half: 0 -> [0,1024), 1 -> [1024,2048)
    const int cq = lane & 31;      // C col = query; A row = position / d
    const int hi = lane >> 5;      // k-slice half within fragment

    union U8 { uint4 u4; short8 s8; };

    // Q B-frags: qf[dm] holds Q[q=cq][d = 16*dm + 8*hi + j]
    const ushort* qbase = q + (size_t)(b * 2048 + i0 + qg * 32 + cq) * 512 + h0 * 64 + hi * 8;
    U8 qf[4];
    #pragma unroll
    for (int dm = 0; dm < 4; dm++) qf[dm].u4 = *(const uint4*)(qbase + dm * 16);

    floatx16 acc0, acc1;           // O^T partials: d 0..31 (acc0), 32..63 (acc1)
    #pragma unroll
    for (int i = 0; i < 16; i++) { acc0[i] = 0.0f; acc1[i] = 0.0f; }
    float lsum = 0.0f;

    // Contiguous slab sources: K/V pre-formatted by gemm_qkv.
    // kblk = ks*32 + s; chunk c = 512 elems (1KB); lane i reads elems i*8..i*8+7.
    const ushort* kSrc = kb + (size_t)b * 131072 + ks * 65536 + lane * 8;
    const ushort* vSrc = vt + (size_t)b * 131072 + ks * 65536 + lane * 8;

    ushort* kT = k_t + ks * 4096;
    ushort* vT = v_t + ks * 4096;

    auto stage = [&](int s, int buf) {
        const int bo = buf * 2048;
        #pragma unroll
        for (int c = 2 * qg; c < 2 * qg + 2; c++) {
            glds16(kSrc + s * 2048 + c * 512, kT + bo + c * 512);
            glds16(vSrc + s * 2048 + c * 512, vT + bo + c * 512);
        }
    };

    auto compute = [&](int buf) {
        const int bo = buf * 2048;
        // QK^T (positions 0..31 of this step, key-permuted in layout)
        floatx16 st;
        #pragma unroll
        for (int i = 0; i < 16; i++) st[i] = -23.0831206f;   // -16*log2(e)
        #pragma unroll
        for (int dm = 0; dm < 4; dm++) {
            U8 kf;
            kf.u4 = *(const uint4*)&kT[bo + (2 * dm + hi) * 256 + cq * 8];
            st = __builtin_amdgcn_mfma_f32_32x32x16_bf16(kf.s8, qf[dm].s8, st, 0, 0, 0);
        }
        float p_[16];
        #pragma unroll
        for (int r = 0; r < 16; r++) p_[r] = __builtin_amdgcn_exp2f(st[r]);
        lsum += (((p_[0] + p_[1]) + (p_[2] + p_[3])) + ((p_[4] + p_[5]) + (p_[6] + p_[7])))
              + (((p_[8] + p_[9]) + (p_[10] + p_[11])) + ((p_[12] + p_[13]) + (p_[14] + p_[15])));
        U8 pb0, pb1;               // PV B-frags: regs 0-7 -> k-slice 0, 8-15 -> slice 1
        pb0.u4.x = pk2(p_[0], p_[1]);   pb0.u4.y = pk2(p_[2], p_[3]);
        pb0.u4.z = pk2(p_[4], p_[5]);   pb0.u4.w = pk2(p_[6], p_[7]);
        pb1.u4.x = pk2(p_[8], p_[9]);   pb1.u4.y = pk2(p_[10], p_[11]);
        pb1.u4.z = pk2(p_[12], p_[13]); pb1.u4.w = pk2(p_[14], p_[15]);
        // PV: O^T(d-tile) += V^T(key-slice) x P^T
        U8 vf;
        vf.u4 = *(const uint4*)&vT[bo + (0 + hi) * 512 + cq * 8];
        acc0 = __builtin_amdgcn_mfma_f32_32x32x16_bf16(vf.s8, pb0.s8, acc0, 0, 0, 0);
        vf.u4 = *(const uint4*)&vT[bo + (2 + hi) * 512 + cq * 8];
        acc0 = __builtin_amdgcn_mfma_f32_32x32x16_bf16(vf.s8, pb1.s8, acc0, 0, 0, 0);
        vf.u4 = *(const uint4*)&vT[bo + (0 + hi) * 512 + (32 + cq) * 8];
        acc1 = __builtin_amdgcn_mfma_f32_32x32x16_bf16(vf.s8, pb0.s8, acc1, 0, 0, 0);
        vf.u4 = *(const uint4*)&vT[bo + (2 + hi) * 512 + (32 + cq) * 8];
        acc1 = __builtin_amdgcn_mfma_f32_32x32x16_bf16(vf.s8, pb1.s8, acc1, 0, 0, 0);
    };

    // prologue: stage step 0 into buf0
    stage(0, 0);
    __syncthreads();

    for (int s = 0; s < 32; s++) {
        const int cur = s & 1;
        if (s < 31) stage(s + 1, cur ^ 1);
        compute(cur);
        __syncthreads();                    // drains next-buf staging; WAR on cur
    }

    // ---- split-K combine via LDS (stride-36 f32: 16B-aligned, 2-way = free) ----
    float* row = (float*)smem + (qg * 64 + lane) * 36;
    if (ks == 1) {
        #pragma unroll
        for (int i = 0; i < 16; i++) { row[i] = acc0[i]; row[16 + i] = acc1[i]; }
        row[32] = lsum;
    }
    __syncthreads();
    if (ks == 1) return;
    #pragma unroll
    for (int i = 0; i < 16; i++) { acc0[i] += row[i]; acc1[i] += row[16 + i]; }
    lsum += row[32];
    lsum += __shfl_xor(lsum, 32);           // combine hi/lo position halves
    float li = 1.0f / fmaxf(lsum, 1e-30f);

    // write out: reg 4t+u of acc0 -> d = u + 8t + 4hi; acc1 -> +32
    ushort* ob = out + (size_t)(b * 2048 + i0 + qg * 32 + cq) * 512 + h0 * 64 + hi * 4;
    #pragma unroll
    for (int t = 0; t < 4; t++) {
        uint2 ov;
        ov.x = pk2(acc0[4 * t] * li, acc0[4 * t + 1] * li);
        ov.y = pk2(acc0[4 * t + 2] * li, acc0[4 * t + 3] * li);
        *(uint2*)(ob + t * 8) = ov;
        ov.x = pk2(acc1[4 * t] * li, acc1[4 * t + 1] * li);
        ov.y = pk2(acc1[4 * t + 2] * li, acc1[4 * t + 3] * li);
        *(uint2*)(ob + 32 + t * 8) = ov;
    }
}

// ---------------------------------------------------------------------------
// Memory plan (bf16 intermediates, ws_size needed = 16MB):
//   d_out: xn [0:16MB) (dead after gemm_qkv) -> ao [0:8MB), woT [8:16MB)
//   ws:    qb [0:8), kb [8:9), vt [9:11), wcatT [11:12.25); y [0:16) after attn.
// Dispatches (6): prep, gemm_qkv, wout_tr, attn, gemm_bt128, ln2.
// ---------------------------------------------------------------------------
extern "C" void kernel_launch(void* const* d_in, const int* in_sizes, int n_in,
                              void* d_out, int out_size, void* d_ws, size_t ws_size,
                              hipStream_t stream) {
    const void* x          = d_in[0];
    const void* norm_g     = d_in[1];
    const void* Wq         = d_in[2];
    const void* Wkv        = d_in[3];
    const void* Wout       = d_in[4];
    const void* out_norm_g = d_in[5];
    const ushort* probe = (const ushort*)d_in[0];
    ushort* ws = (ushort*)d_ws;

    const size_t M1 = 1024 * 1024 / 2;  // bf16 elems per MB
    ushort* xn    = (ushort*)d_out;
    ushort* ao    = (ushort*)d_out;
    ushort* woT   = (ushort*)((char*)d_out + (8u << 20));
    ushort* qb    = ws;
    ushort* kb    = ws + 8 * M1;
    ushort* vt    = ws + 9 * M1;
    ushort* wcatT = ws + 11 * M1;
    ushort* y     = ws;

    // prep: LN1 + Wq^T + Wkv^T fused
    prep_kernel<<<8832, 256, 0, stream>>>(x, norm_g, Wq, Wkv, xn, wcatT, probe);

    // fused q/k/v projection + l2norm + K/V slab formatting
    gemm_qkv<<<dim3(10, 128), 256, 0, stream>>>(xn, wcatT, qb, kb, vt);

    // Wout^T -> d_out[8:16MB) (xn dead now)
    wout_tr_kernel<<<dim3(32, 16), 256, 0, stream>>>(Wout, woT, probe);

    // attention -> ao
    attn_kernel<<<dim3(32, 8, 4), 256, 0, stream>>>(qb, kb, vt, ao);

    // y = ao @ Wout  (128-tile, global_load_lds)
    gemm_bt128<<<dim3(8, 64), 256, 0, stream>>>(ao, woT, y, 8192, 1024, 512);

    // LN2: y -> final output
    ln2_kernel<<<8192, 256, 0, stream>>>(y, out_norm_g, d_out, probe);
}

// Round 7
// 206.376 us; speedup vs baseline: 1.0999x; 1.0064x over previous
//
#include <hip/hip_runtime.h>
#include <hip/hip_bf16.h>

typedef __attribute__((ext_vector_type(8))) short short8;
typedef __attribute__((ext_vector_type(4))) float floatx4;
typedef __attribute__((ext_vector_type(16))) float floatx16;

__device__ __forceinline__ float bf2f(ushort u) {
    return __uint_as_float(((unsigned int)u) << 16);
}
__device__ __forceinline__ ushort f2bf(float f) {
    unsigned int u = __float_as_uint(f);
    unsigned int r = (u + 0x7FFFu + ((u >> 16) & 1u)) >> 16;
    return (ushort)r;
}
// packed f32x2 -> bf16x2
__device__ __forceinline__ unsigned int pk2(float a, float b) {
    union { __hip_bfloat162 h; unsigned int u; } cv;
    cv.h = __float22bfloat162_rn(make_float2(a, b));
    return cv.u;
}
__device__ __forceinline__ float scrub(float v, float lim) {
    return fminf(fmaxf(v, -lim), lim);
}
// async global->LDS, 16B per lane (lane i lands at wave-uniform lds base + 16*i)
__device__ __forceinline__ void glds16(const ushort* g, ushort* l) {
    __builtin_amdgcn_global_load_lds((const __attribute__((address_space(1))) void*)g,
                                     (__attribute__((address_space(3))) void*)l, 16, 0, 0);
}

// Wave-uniform dtype probe on x: bf16 N(0,1) data has exponent byte in [117,131]
// ~99% at even ushort indices; fp32-as-ushort gives ~6%. 32 samples, thr 16.
__device__ __forceinline__ bool detect_bf16(const ushort* __restrict__ probe) {
    const int lane = threadIdx.x & 63;
    ushort u = probe[(lane & 31) * 2];
    int e = (u >> 7) & 0xFF;
    bool pl = (e >= 117) && (e <= 131) && (lane < 32);
    return __popcll(__ballot(pl)) >= 16;
}

// ---------------------------------------------------------------------------
// Transpose helper (256 threads).
// ---------------------------------------------------------------------------
__device__ __forceinline__ void do_transpose(const void* __restrict__ in,
                                             ushort* __restrict__ out,
                                             int bx, int by, int in_rs, int out_rs,
                                             bool ib, ushort* tile /*32x33*/) {
    const int tx = threadIdx.x & 31, ty = threadIdx.x >> 5;
    #pragma unroll
    for (int rr = 0; rr < 32; rr += 8) {
        size_t idx = (size_t)(by * 32 + ty + rr) * in_rs + bx * 32 + tx;
        float v = ib ? bf2f(((const ushort*)in)[idx]) : ((const float*)in)[idx];
        tile[(ty + rr) * 33 + tx] = f2bf(scrub(v, 1e8f));
    }
    __syncthreads();
    #pragma unroll
    for (int rr = 0; rr < 32; rr += 8) {
        int r = bx * 32 + ty + rr;
        int c = by * 32 + tx;
        out[(size_t)r * out_rs + c] = tile[tx * 33 + (ty + rr)];
    }
}

// ---------------------------------------------------------------------------
// prep: fused LN1 (blocks 0..8191) + Wq^T (8192..8703) + Wkv^T (8704..8831).
// ---------------------------------------------------------------------------
__global__ __launch_bounds__(256) void prep_kernel(const void* __restrict__ xin,
                                                   const void* __restrict__ gin,
                                                   const void* __restrict__ Wq,
                                                   const void* __restrict__ Wkv,
                                                   ushort* __restrict__ xn,
                                                   ushort* __restrict__ wcatT,
                                                   const ushort* __restrict__ probe) {
    const bool ib = detect_bf16(probe);
    const int id = blockIdx.x;
    __shared__ ushort tile[32 * 33];
    __shared__ float red[8];

    if (id >= 8192) {
        if (id < 8704) {
            int t = id - 8192;                  // Wq[1024][512] -> wcatT[0:512)[1024]
            do_transpose(Wq, wcatT, t & 15, t >> 4, 512, 1024, ib, tile);
        } else {
            int t = id - 8704;                  // Wkv[1024][128] -> wcatT[512:640)[1024]
            do_transpose(Wkv, wcatT + (size_t)512 * 1024, t & 3, t >> 2, 128, 1024, ib, tile);
        }
        return;
    }

    const int row = id;
    const int tid = threadIdx.x;
    float v0, v1, v2, v3, g0, g1, g2, g3;
    if (ib) {
        uint2 u = *(const uint2*)((const ushort*)xin + (size_t)row * 1024 + tid * 4);
        v0 = bf2f((ushort)(u.x & 0xFFFF)); v1 = bf2f((ushort)(u.x >> 16));
        v2 = bf2f((ushort)(u.y & 0xFFFF)); v3 = bf2f((ushort)(u.y >> 16));
        uint2 gu = *(const uint2*)((const ushort*)gin + tid * 4);
        g0 = bf2f((ushort)(gu.x & 0xFFFF)); g1 = bf2f((ushort)(gu.x >> 16));
        g2 = bf2f((ushort)(gu.y & 0xFFFF)); g3 = bf2f((ushort)(gu.y >> 16));
    } else {
        float4 xv = *(const float4*)((const float*)xin + (size_t)row * 1024 + tid * 4);
        v0 = xv.x; v1 = xv.y; v2 = xv.z; v3 = xv.w;
        float4 gv = *(const float4*)((const float*)gin + tid * 4);
        g0 = gv.x; g1 = gv.y; g2 = gv.z; g3 = gv.w;
    }
    v0 = scrub(v0, 1e8f); v1 = scrub(v1, 1e8f); v2 = scrub(v2, 1e8f); v3 = scrub(v3, 1e8f);
    g0 = scrub(g0, 1e8f); g1 = scrub(g1, 1e8f); g2 = scrub(g2, 1e8f); g3 = scrub(g3, 1e8f);

    float s  = v0 + v1 + v2 + v3;
    float sq = v0 * v0 + v1 * v1 + v2 * v2 + v3 * v3;
    #pragma unroll
    for (int off = 1; off < 64; off <<= 1) {
        s  += __shfl_xor(s, off);
        sq += __shfl_xor(sq, off);
    }
    const int w = tid >> 6, lane = tid & 63;
    if (lane == 0) { red[w] = s; red[w + 4] = sq; }
    __syncthreads();
    float S  = red[0] + red[1] + red[2] + red[3];
    float SQ = red[4] + red[5] + red[6] + red[7];

    float mean = S * (1.0f / 1024.0f);
    float var  = SQ * (1.0f / 1024.0f) - mean * mean;
    float rstd = rsqrtf(fmaxf(var, 0.0f) + 1e-5f);

    uint2 ov;
    ov.x = pk2((v0 - mean) * rstd * g0, (v1 - mean) * rstd * g1);
    ov.y = pk2((v2 - mean) * rstd * g2, (v3 - mean) * rstd * g3);
    *(uint2*)(xn + (size_t)row * 1024 + tid * 4) = ov;
}

// ---------------------------------------------------------------------------
// Standalone Wout transpose (r6-proven position: after gemm_qkv, xn dead).
// ---------------------------------------------------------------------------
__global__ __launch_bounds__(256) void wout_tr_kernel(const void* __restrict__ Wout,
                                                      ushort* __restrict__ woT,
                                                      const ushort* __restrict__ probe) {
    const bool ib = detect_bf16(probe);
    __shared__ ushort tile[32 * 33];
    do_transpose(Wout, woT, blockIdx.x, blockIdx.y, 1024, 512, ib, tile);
}

// ---------------------------------------------------------------------------
// LN2: input bf16, gamma + OUTPUT dtype detected.
// ---------------------------------------------------------------------------
__global__ __launch_bounds__(256) void ln2_kernel(const ushort* __restrict__ y,
                                                  const void* __restrict__ gin,
                                                  void* __restrict__ out,
                                                  const ushort* __restrict__ probe) {
    const bool ob = detect_bf16(probe);
    const int row = blockIdx.x;
    const int tid = threadIdx.x;

    uint2 u = *(const uint2*)(y + (size_t)row * 1024 + tid * 4);
    float v0 = scrub(bf2f((ushort)(u.x & 0xFFFF)), 1e8f);
    float v1 = scrub(bf2f((ushort)(u.x >> 16)),    1e8f);
    float v2 = scrub(bf2f((ushort)(u.y & 0xFFFF)), 1e8f);
    float v3 = scrub(bf2f((ushort)(u.y >> 16)),    1e8f);

    float g0, g1, g2, g3;
    if (ob) {
        uint2 gu = *(const uint2*)((const ushort*)gin + tid * 4);
        g0 = bf2f((ushort)(gu.x & 0xFFFF)); g1 = bf2f((ushort)(gu.x >> 16));
        g2 = bf2f((ushort)(gu.y & 0xFFFF)); g3 = bf2f((ushort)(gu.y >> 16));
    } else {
        float4 gv = *(const float4*)((const float*)gin + tid * 4);
        g0 = gv.x; g1 = gv.y; g2 = gv.z; g3 = gv.w;
    }
    g0 = scrub(g0, 1e8f); g1 = scrub(g1, 1e8f); g2 = scrub(g2, 1e8f); g3 = scrub(g3, 1e8f);

    float s  = v0 + v1 + v2 + v3;
    float sq = v0 * v0 + v1 * v1 + v2 * v2 + v3 * v3;
    #pragma unroll
    for (int off = 1; off < 64; off <<= 1) {
        s  += __shfl_xor(s, off);
        sq += __shfl_xor(sq, off);
    }
    __shared__ float red[8];
    const int w = tid >> 6, lane = tid & 63;
    if (lane == 0) { red[w] = s; red[w + 4] = sq; }
    __syncthreads();
    float S  = red[0] + red[1] + red[2] + red[3];
    float SQ = red[4] + red[5] + red[6] + red[7];

    float mean = S * (1.0f / 1024.0f);
    float var  = SQ * (1.0f / 1024.0f) - mean * mean;
    float rstd = rsqrtf(fmaxf(var, 0.0f) + 1e-5f);

    float o0 = (v0 - mean) * rstd * g0;
    float o1 = (v1 - mean) * rstd * g1;
    float o2 = (v2 - mean) * rstd * g2;
    float o3 = (v3 - mean) * rstd * g3;
    if (ob) {
        uint2 ov;
        ov.x = pk2(o0, o1);
        ov.y = pk2(o2, o3);
        *(uint2*)((ushort*)out + (size_t)row * 1024 + tid * 4) = ov;
    } else {
        *(float4*)((float*)out + (size_t)row * 1024 + tid * 4) = make_float4(o0, o1, o2, o3);
    }
}

// ---------------------------------------------------------------------------
// Fused QKV GEMM with global_load_lds staging.
// grid (10,128): bx<8 q (l2norm, pre-scaled by log2(e) for exp2 softmax),
// bx==8 k (l2norm -> SLAB layout), bx==9 v (-> SLAB layout).
//   K: kb[b][kblk32][d-oct8][pos32][e8], pos = bitswap23(key&31) (bakes the
//      in-register-P permutation into the layout).
//   V: vt[b][kblk32][k-oct4][d64][kk8].
// ---------------------------------------------------------------------------
__global__ __launch_bounds__(256) void gemm_qkv(const ushort* __restrict__ A,
                                                const ushort* __restrict__ Bt,
                                                ushort* __restrict__ qb,
                                                ushort* __restrict__ kb,
                                                ushort* __restrict__ vt) {
    __shared__ ushort a_t[64 * 32];
    __shared__ ushort b_t[64 * 32];

    const int bx = blockIdx.x;
    const int n0 = bx * 64, m0 = blockIdx.y * 64;
    const int tid = threadIdx.x;
    const int w = tid >> 6, lane = tid & 63;
    const int fm = lane & 15, quad = lane >> 4;
    const int K = 1024;

    // glds chunk map: thread t -> row t>>2 (0..63), k-octet t&3
    const ushort* ag = A + (size_t)(m0 + (tid >> 2)) * K + (tid & 3) * 8;
    const ushort* bg = Bt + (size_t)(n0 + (tid >> 2)) * K + (tid & 3) * 8;
    ushort* la = a_t + w * 512;   // wave-uniform LDS base
    ushort* lb = b_t + w * 512;

    floatx4 acc[4];
    floatx4 zero4 = {0.0f, 0.0f, 0.0f, 0.0f};
    #pragma unroll
    for (int nt = 0; nt < 4; nt++) acc[nt] = zero4;

    union U8 { uint4 u4; short8 s8; };

    for (int k0 = 0; k0 < K; k0 += 32) {
        __syncthreads();                   // prior iter's frag reads done
        glds16(ag + k0, la);
        glds16(bg + k0, lb);
        __syncthreads();                   // vmcnt drained before reads

        U8 af;
        af.u4 = *(const uint4*)&a_t[(w * 16 + fm) * 32 + quad * 8];
        #pragma unroll
        for (int nt = 0; nt < 4; nt++) {
            U8 bf;
            bf.u4 = *(const uint4*)&b_t[(nt * 16 + fm) * 32 + quad * 8];
            acc[nt] = __builtin_amdgcn_mfma_f32_16x16x32_bf16(af.s8, bf.s8, acc[nt], 0, 0, 0);
        }
    }

    if (bx < 9) {
        // q gets 4*log2(e) so attn's QK accumulates S*log2e -> bare exp2.
        const float qsc = (bx < 8) ? 5.7707801636f : 4.0f;
        float sc[4];
        #pragma unroll
        for (int r = 0; r < 4; r++) {
            float ss = acc[0][r] * acc[0][r] + acc[1][r] * acc[1][r]
                     + acc[2][r] * acc[2][r] + acc[3][r] * acc[3][r];
            ss += __shfl_xor(ss, 1);
            ss += __shfl_xor(ss, 2);
            ss += __shfl_xor(ss, 4);
            ss += __shfl_xor(ss, 8);
            sc[r] = qsc / fmaxf(sqrtf(ss), 1e-12f);
        }
        if (bx < 8) {
            ushort* op = qb + n0;
            #pragma unroll
            for (int nt = 0; nt < 4; nt++)
                #pragma unroll
                for (int r = 0; r < 4; r++)
                    op[(size_t)(m0 + w * 16 + quad * 4 + r) * 512 + nt * 16 + fm] =
                        f2bf(acc[nt][r] * sc[r]);
        } else {
            // K slab write: key = m0 + w*16 + quad*4 + r, d = nt*16 + fm.
            // idx = bb*131072 + kblk*2048 + (d>>3)*256 + bitswap23(key&31)*8 + (d&7)
            const int bb = m0 >> 11;
            const int kblk = ((m0 & 2047) >> 5) + (w >> 1);
            const int qsw = ((quad & 1) << 1) | (quad >> 1);   // bitswap23 of quad
            ushort* op = kb + (size_t)bb * 131072 + kblk * 2048
                       + (w & 1) * 128 + qsw * 32 + (fm & 7);
            #pragma unroll
            for (int nt = 0; nt < 4; nt++) {
                const int oct = nt * 2 + (fm >> 3);
                #pragma unroll
                for (int r = 0; r < 4; r++)
                    op[oct * 256 + r * 8] = f2bf(acc[nt][r] * sc[r]);
            }
        }
    } else {
        // V slab write: key = m0 + w*16 + quad*4 + r, d = nt*16 + fm.
        // idx = bb*131072 + kblk*2048 + ((key>>3)&3)*512 + d*8 + (key&7)
        const int bb = m0 >> 11;
        const int kblk = ((m0 & 2047) >> 5) + (w >> 1);
        const int koct = ((w & 1) * 2 + (quad >> 1)) & 3;
        ushort* vb = vt + (size_t)bb * 131072 + kblk * 2048 + koct * 512 + (quad & 1) * 4;
        #pragma unroll
        for (int nt = 0; nt < 4; nt++) {
            uint2 pv;
            pv.x = pk2(acc[nt][0], acc[nt][1]);
            pv.y = pk2(acc[nt][2], acc[nt][3]);
            *(uint2*)(vb + (nt * 16 + fm) * 8) = pv;
        }
    }
}

// ---------------------------------------------------------------------------
// Out-projection GEMM, m97-style: 128x128 tile, BK=32, global_load_lds w=16.
// ---------------------------------------------------------------------------
__global__ __launch_bounds__(256) void gemm_bt128(const ushort* __restrict__ A,
                                                  const ushort* __restrict__ Bt,
                                                  ushort* __restrict__ C,
                                                  int M, int N, int K) {
    __shared__ ushort a_t[128][32];
    __shared__ ushort b_t[128][32];

    const int n0 = blockIdx.x * 128, m0 = blockIdx.y * 128;
    const int tid = threadIdx.x;
    const int w = tid >> 6, lane = tid & 63;
    const int fm = lane & 15, quad = lane >> 4;

    const int c0 = tid, c1 = tid + 256;
    const ushort* ag0 = A + (size_t)(m0 + (c0 >> 2)) * K + (c0 & 3) * 8;
    const ushort* ag1 = A + (size_t)(m0 + (c1 >> 2)) * K + (c1 & 3) * 8;
    const ushort* bg0 = Bt + (size_t)(n0 + (c0 >> 2)) * K + (c0 & 3) * 8;
    const ushort* bg1 = Bt + (size_t)(n0 + (c1 >> 2)) * K + (c1 & 3) * 8;
    ushort* la0 = &a_t[0][0] + w * 512;
    ushort* la1 = &a_t[0][0] + 2048 + w * 512;
    ushort* lb0 = &b_t[0][0] + w * 512;
    ushort* lb1 = &b_t[0][0] + 2048 + w * 512;

    floatx4 acc[2][8];
    floatx4 zero4 = {0.0f, 0.0f, 0.0f, 0.0f};
    #pragma unroll
    for (int mt = 0; mt < 2; mt++)
        #pragma unroll
        for (int nt = 0; nt < 8; nt++) acc[mt][nt] = zero4;

    union U8 { uint4 u4; short8 s8; };

    for (int k0 = 0; k0 < K; k0 += 32) {
        __syncthreads();
        glds16(ag0 + k0, la0);
        glds16(ag1 + k0, la1);
        glds16(bg0 + k0, lb0);
        glds16(bg1 + k0, lb1);
        __syncthreads();

        U8 af[2];
        #pragma unroll
        for (int mt = 0; mt < 2; mt++)
            af[mt].u4 = *(const uint4*)&a_t[w * 32 + mt * 16 + fm][quad * 8];
        #pragma unroll
        for (int nt = 0; nt < 8; nt++) {
            U8 bf;
            bf.u4 = *(const uint4*)&b_t[nt * 16 + fm][quad * 8];
            acc[0][nt] = __builtin_amdgcn_mfma_f32_16x16x32_bf16(af[0].s8, bf.s8, acc[0][nt], 0, 0, 0);
            acc[1][nt] = __builtin_amdgcn_mfma_f32_16x16x32_bf16(af[1].s8, bf.s8, acc[1][nt], 0, 0, 0);
        }
    }

    #pragma unroll
    for (int mt = 0; mt < 2; mt++)
        #pragma unroll
        for (int nt = 0; nt < 8; nt++)
            #pragma unroll
            for (int r = 0; r < 4; r++)
                C[(size_t)(m0 + w * 32 + mt * 16 + quad * 4 + r) * N + n0 + nt * 16 + fm] =
                    f2bf(acc[mt][nt][r]);
}

// ---------------------------------------------------------------------------
// Flash attention v6: r5 compute (validated) with 8-wave blocks.
//
// r5 post-mortem @54us: MFMA 33k cyc (26% = MfmaUtil), ds_read 49k, DMA LDS
// writes 33k, 128 full-drain barriers/CU -> LDS pipe + barrier cadence bound.
// v6: 512 thr = 4 q-groups x 2 key-splits. The same 8KB/step staging now
// serves 128 queries (2x) -> glds16 count and DMA-write cycles HALVE; one
// barrier per 64 block-MFMAs (2x amortization). Same 16 waves/CU (2 blocks
// x 8 waves); per-thread code identical to r5 (VGPR 60 @ 128-reg cap -> no
// spill at (512,4)).
// LDS: staging 32KB; split-K combine 256 rows x 34 f32 = 34.8KB total.
// ---------------------------------------------------------------------------
__global__ __launch_bounds__(512, 4) void attn_kernel(const ushort* __restrict__ q,
                                                      const ushort* __restrict__ kb,
                                                      const ushort* __restrict__ vt,
                                                      ushort* __restrict__ out) {
    __shared__ ushort smem[17408];          // 34.8 KB (staging 32KB | combine 34.8KB)
    ushort* k_t = smem;                     // [ks][buf][oct8][pos32][8]
    ushort* v_t = smem + 8192;              // [ks][buf][oct4][d64][8]

    const int i0 = blockIdx.x * 128;
    const int h0 = blockIdx.y, b = blockIdx.z;
    const int tid = threadIdx.x, w = tid >> 6, lane = tid & 63;
    const int qg = w & 3;          // query group of 32 (0..3)
    const int ks = w >> 2;         // key half: 0 -> [0,1024), 1 -> [1024,2048)
    const int cq = lane & 31;      // C col = query; A row = position / d
    const int hi = lane >> 5;      // k-slice half within fragment

    union U8 { uint4 u4; short8 s8; };

    // Q B-frags: qf[dm] holds Q[q=cq][d = 16*dm + 8*hi + j]
    const ushort* qbase = q + (size_t)(b * 2048 + i0 + qg * 32 + cq) * 512 + h0 * 64 + hi * 8;
    U8 qf[4];
    #pragma unroll
    for (int dm = 0; dm < 4; dm++) qf[dm].u4 = *(const uint4*)(qbase + dm * 16);

    floatx16 acc0, acc1;           // O^T partials: d 0..31 (acc0), 32..63 (acc1)
    #pragma unroll
    for (int i = 0; i < 16; i++) { acc0[i] = 0.0f; acc1[i] = 0.0f; }
    float lsum = 0.0f;

    // Contiguous slab sources: K/V pre-formatted by gemm_qkv.
    // kblk = ks*32 + s; chunk qg = 512 elems (1KB); lane i reads elems i*8..i*8+7.
    const ushort* kSrc = kb + (size_t)b * 131072 + ks * 65536 + lane * 8;
    const ushort* vSrc = vt + (size_t)b * 131072 + ks * 65536 + lane * 8;

    ushort* kT = k_t + ks * 4096;
    ushort* vT = v_t + ks * 4096;

    // 4 q-group waves of a ks split the 8 chunks: wave qg stages K chunk qg
    // and V chunk qg (2 glds16/wave/step).
    auto stage = [&](int s, int buf) {
        const int bo = buf * 2048;
        glds16(kSrc + s * 2048 + qg * 512, kT + bo + qg * 512);
        glds16(vSrc + s * 2048 + qg * 512, vT + bo + qg * 512);
    };

    auto compute = [&](int buf) {
        const int bo = buf * 2048;
        // QK^T (positions 0..31 of this step, key-permuted in layout)
        floatx16 st;
        #pragma unroll
        for (int i = 0; i < 16; i++) st[i] = -23.0831206f;   // -16*log2(e)
        #pragma unroll
        for (int dm = 0; dm < 4; dm++) {
            U8 kf;
            kf.u4 = *(const uint4*)&kT[bo + (2 * dm + hi) * 256 + cq * 8];
            st = __builtin_amdgcn_mfma_f32_32x32x16_bf16(kf.s8, qf[dm].s8, st, 0, 0, 0);
        }
        float p_[16];
        #pragma unroll
        for (int r = 0; r < 16; r++) p_[r] = __builtin_amdgcn_exp2f(st[r]);
        lsum += (((p_[0] + p_[1]) + (p_[2] + p_[3])) + ((p_[4] + p_[5]) + (p_[6] + p_[7])))
              + (((p_[8] + p_[9]) + (p_[10] + p_[11])) + ((p_[12] + p_[13]) + (p_[14] + p_[15])));
        U8 pb0, pb1;               // PV B-frags: regs 0-7 -> k-slice 0, 8-15 -> slice 1
        pb0.u4.x = pk2(p_[0], p_[1]);   pb0.u4.y = pk2(p_[2], p_[3]);
        pb0.u4.z = pk2(p_[4], p_[5]);   pb0.u4.w = pk2(p_[6], p_[7]);
        pb1.u4.x = pk2(p_[8], p_[9]);   pb1.u4.y = pk2(p_[10], p_[11]);
        pb1.u4.z = pk2(p_[12], p_[13]); pb1.u4.w = pk2(p_[14], p_[15]);
        // PV: O^T(d-tile) += V^T(key-slice) x P^T
        U8 vf;
        vf.u4 = *(const uint4*)&vT[bo + (0 + hi) * 512 + cq * 8];
        acc0 = __builtin_amdgcn_mfma_f32_32x32x16_bf16(vf.s8, pb0.s8, acc0, 0, 0, 0);
        vf.u4 = *(const uint4*)&vT[bo + (2 + hi) * 512 + cq * 8];
        acc0 = __builtin_amdgcn_mfma_f32_32x32x16_bf16(vf.s8, pb1.s8, acc0, 0, 0, 0);
        vf.u4 = *(const uint4*)&vT[bo + (0 + hi) * 512 + (32 + cq) * 8];
        acc1 = __builtin_amdgcn_mfma_f32_32x32x16_bf16(vf.s8, pb0.s8, acc1, 0, 0, 0);
        vf.u4 = *(const uint4*)&vT[bo + (2 + hi) * 512 + (32 + cq) * 8];
        acc1 = __builtin_amdgcn_mfma_f32_32x32x16_bf16(vf.s8, pb1.s8, acc1, 0, 0, 0);
    };

    // prologue: stage step 0 into buf0
    stage(0, 0);
    __syncthreads();

    for (int s = 0; s < 32; s++) {
        const int cur = s & 1;
        if (s < 31) stage(s + 1, cur ^ 1);
        compute(cur);
        __syncthreads();                    // drains next-buf staging; WAR on cur
    }

    // ---- split-K combine via LDS (stride-34 f32: lanes 16 apart alias = free) ----
    float* row = (float*)smem + (qg * 64 + lane) * 34;
    if (ks == 1) {
        #pragma unroll
        for (int i = 0; i < 16; i++) { row[i] = acc0[i]; row[16 + i] = acc1[i]; }
        row[32] = lsum;
    }
    __syncthreads();
    if (ks == 1) return;
    #pragma unroll
    for (int i = 0; i < 16; i++) { acc0[i] += row[i]; acc1[i] += row[16 + i]; }
    lsum += row[32];
    lsum += __shfl_xor(lsum, 32);           // combine hi/lo position halves
    float li = 1.0f / fmaxf(lsum, 1e-30f);

    // write out: reg 4t+u of acc0 -> d = u + 8t + 4hi; acc1 -> +32
    ushort* ob = out + (size_t)(b * 2048 + i0 + qg * 32 + cq) * 512 + h0 * 64 + hi * 4;
    #pragma unroll
    for (int t = 0; t < 4; t++) {
        uint2 ov;
        ov.x = pk2(acc0[4 * t] * li, acc0[4 * t + 1] * li);
        ov.y = pk2(acc0[4 * t + 2] * li, acc0[4 * t + 3] * li);
        *(uint2*)(ob + t * 8) = ov;
        ov.x = pk2(acc1[4 * t] * li, acc1[4 * t + 1] * li);
        ov.y = pk2(acc1[4 * t + 2] * li, acc1[4 * t + 3] * li);
        *(uint2*)(ob + 32 + t * 8) = ov;
    }
}

// ---------------------------------------------------------------------------
// Memory plan (bf16 intermediates, ws_size needed = 16MB):
//   d_out: xn [0:16MB) (dead after gemm_qkv) -> ao [0:8MB), woT [8:16MB)
//   ws:    qb [0:8), kb [8:9), vt [9:11), wcatT [11:12.25); y [0:16) after attn.
// Dispatches (6): prep, gemm_qkv, wout_tr, attn, gemm_bt128, ln2.
// ---------------------------------------------------------------------------
extern "C" void kernel_launch(void* const* d_in, const int* in_sizes, int n_in,
                              void* d_out, int out_size, void* d_ws, size_t ws_size,
                              hipStream_t stream) {
    const void* x          = d_in[0];
    const void* norm_g     = d_in[1];
    const void* Wq         = d_in[2];
    const void* Wkv        = d_in[3];
    const void* Wout       = d_in[4];
    const void* out_norm_g = d_in[5];
    const ushort* probe = (const ushort*)d_in[0];
    ushort* ws = (ushort*)d_ws;

    const size_t M1 = 1024 * 1024 / 2;  // bf16 elems per MB
    ushort* xn    = (ushort*)d_out;
    ushort* ao    = (ushort*)d_out;
    ushort* woT   = (ushort*)((char*)d_out + (8u << 20));
    ushort* qb    = ws;
    ushort* kb    = ws + 8 * M1;
    ushort* vt    = ws + 9 * M1;
    ushort* wcatT = ws + 11 * M1;
    ushort* y     = ws;

    // prep: LN1 + Wq^T + Wkv^T fused
    prep_kernel<<<8832, 256, 0, stream>>>(x, norm_g, Wq, Wkv, xn, wcatT, probe);

    // fused q/k/v projection + l2norm + K/V slab formatting
    gemm_qkv<<<dim3(10, 128), 256, 0, stream>>>(xn, wcatT, qb, kb, vt);

    // Wout^T -> d_out[8:16MB) (xn dead now)
    wout_tr_kernel<<<dim3(32, 16), 256, 0, stream>>>(Wout, woT, probe);

    // attention -> ao
    attn_kernel<<<dim3(16, 8, 4), 512, 0, stream>>>(qb, kb, vt, ao);

    // y = ao @ Wout  (128-tile, global_load_lds)
    gemm_bt128<<<dim3(8, 64), 256, 0, stream>>>(ao, woT, y, 8192, 1024, 512);

    // LN2: y -> final output
    ln2_kernel<<<8192, 256, 0, stream>>>(y, out_norm_g, d_out, probe);
}

// Round 8
// 206.175 us; speedup vs baseline: 1.1010x; 1.0010x over previous
//
#include <hip/hip_runtime.h>
#include <hip/hip_bf16.h>

typedef __attribute__((ext_vector_type(8))) short short8;
typedef __attribute__((ext_vector_type(4))) float floatx4;
typedef __attribute__((ext_vector_type(16))) float floatx16;

__device__ __forceinline__ float bf2f(ushort u) {
    return __uint_as_float(((unsigned int)u) << 16);
}
__device__ __forceinline__ ushort f2bf(float f) {
    unsigned int u = __float_as_uint(f);
    unsigned int r = (u + 0x7FFFu + ((u >> 16) & 1u)) >> 16;
    return (ushort)r;
}
// packed f32x2 -> bf16x2
__device__ __forceinline__ unsigned int pk2(float a, float b) {
    union { __hip_bfloat162 h; unsigned int u; } cv;
    cv.h = __float22bfloat162_rn(make_float2(a, b));
    return cv.u;
}
__device__ __forceinline__ float scrub(float v, float lim) {
    return fminf(fmaxf(v, -lim), lim);
}
// async global->LDS, 16B per lane (lane i lands at wave-uniform lds base + 16*i)
__device__ __forceinline__ void glds16(const ushort* g, ushort* l) {
    __builtin_amdgcn_global_load_lds((const __attribute__((address_space(1))) void*)g,
                                     (__attribute__((address_space(3))) void*)l, 16, 0, 0);
}

// Wave-uniform dtype probe on x: bf16 N(0,1) data has exponent byte in [117,131]
// ~99% at even ushort indices; fp32-as-ushort gives ~6%. 32 samples, thr 16.
__device__ __forceinline__ bool detect_bf16(const ushort* __restrict__ probe) {
    const int lane = threadIdx.x & 63;
    ushort u = probe[(lane & 31) * 2];
    int e = (u >> 7) & 0xFF;
    bool pl = (e >= 117) && (e <= 131) && (lane < 32);
    return __popcll(__ballot(pl)) >= 16;
}

// ---------------------------------------------------------------------------
// Transpose helper (256 threads).
// ---------------------------------------------------------------------------
__device__ __forceinline__ void do_transpose(const void* __restrict__ in,
                                             ushort* __restrict__ out,
                                             int bx, int by, int in_rs, int out_rs,
                                             bool ib, ushort* tile /*32x33*/) {
    const int tx = threadIdx.x & 31, ty = threadIdx.x >> 5;
    #pragma unroll
    for (int rr = 0; rr < 32; rr += 8) {
        size_t idx = (size_t)(by * 32 + ty + rr) * in_rs + bx * 32 + tx;
        float v = ib ? bf2f(((const ushort*)in)[idx]) : ((const float*)in)[idx];
        tile[(ty + rr) * 33 + tx] = f2bf(scrub(v, 1e8f));
    }
    __syncthreads();
    #pragma unroll
    for (int rr = 0; rr < 32; rr += 8) {
        int r = bx * 32 + ty + rr;
        int c = by * 32 + tx;
        out[(size_t)r * out_rs + c] = tile[tx * 33 + (ty + rr)];
    }
}

// ---------------------------------------------------------------------------
// prep: fused LN1 (blocks 0..8191) + Wq^T (8192..8703) + Wkv^T (8704..8831).
// ---------------------------------------------------------------------------
__global__ __launch_bounds__(256) void prep_kernel(const void* __restrict__ xin,
                                                   const void* __restrict__ gin,
                                                   const void* __restrict__ Wq,
                                                   const void* __restrict__ Wkv,
                                                   ushort* __restrict__ xn,
                                                   ushort* __restrict__ wcatT,
                                                   const ushort* __restrict__ probe) {
    const bool ib = detect_bf16(probe);
    const int id = blockIdx.x;
    __shared__ ushort tile[32 * 33];
    __shared__ float red[8];

    if (id >= 8192) {
        if (id < 8704) {
            int t = id - 8192;                  // Wq[1024][512] -> wcatT[0:512)[1024]
            do_transpose(Wq, wcatT, t & 15, t >> 4, 512, 1024, ib, tile);
        } else {
            int t = id - 8704;                  // Wkv[1024][128] -> wcatT[512:640)[1024]
            do_transpose(Wkv, wcatT + (size_t)512 * 1024, t & 3, t >> 2, 128, 1024, ib, tile);
        }
        return;
    }

    const int row = id;
    const int tid = threadIdx.x;
    float v0, v1, v2, v3, g0, g1, g2, g3;
    if (ib) {
        uint2 u = *(const uint2*)((const ushort*)xin + (size_t)row * 1024 + tid * 4);
        v0 = bf2f((ushort)(u.x & 0xFFFF)); v1 = bf2f((ushort)(u.x >> 16));
        v2 = bf2f((ushort)(u.y & 0xFFFF)); v3 = bf2f((ushort)(u.y >> 16));
        uint2 gu = *(const uint2*)((const ushort*)gin + tid * 4);
        g0 = bf2f((ushort)(gu.x & 0xFFFF)); g1 = bf2f((ushort)(gu.x >> 16));
        g2 = bf2f((ushort)(gu.y & 0xFFFF)); g3 = bf2f((ushort)(gu.y >> 16));
    } else {
        float4 xv = *(const float4*)((const float*)xin + (size_t)row * 1024 + tid * 4);
        v0 = xv.x; v1 = xv.y; v2 = xv.z; v3 = xv.w;
        float4 gv = *(const float4*)((const float*)gin + tid * 4);
        g0 = gv.x; g1 = gv.y; g2 = gv.z; g3 = gv.w;
    }
    v0 = scrub(v0, 1e8f); v1 = scrub(v1, 1e8f); v2 = scrub(v2, 1e8f); v3 = scrub(v3, 1e8f);
    g0 = scrub(g0, 1e8f); g1 = scrub(g1, 1e8f); g2 = scrub(g2, 1e8f); g3 = scrub(g3, 1e8f);

    float s  = v0 + v1 + v2 + v3;
    float sq = v0 * v0 + v1 * v1 + v2 * v2 + v3 * v3;
    #pragma unroll
    for (int off = 1; off < 64; off <<= 1) {
        s  += __shfl_xor(s, off);
        sq += __shfl_xor(sq, off);
    }
    const int w = tid >> 6, lane = tid & 63;
    if (lane == 0) { red[w] = s; red[w + 4] = sq; }
    __syncthreads();
    float S  = red[0] + red[1] + red[2] + red[3];
    float SQ = red[4] + red[5] + red[6] + red[7];

    float mean = S * (1.0f / 1024.0f);
    float var  = SQ * (1.0f / 1024.0f) - mean * mean;
    float rstd = rsqrtf(fmaxf(var, 0.0f) + 1e-5f);

    uint2 ov;
    ov.x = pk2((v0 - mean) * rstd * g0, (v1 - mean) * rstd * g1);
    ov.y = pk2((v2 - mean) * rstd * g2, (v3 - mean) * rstd * g3);
    *(uint2*)(xn + (size_t)row * 1024 + tid * 4) = ov;
}

// ---------------------------------------------------------------------------
// Standalone Wout transpose (r6-proven position: after gemm_qkv, xn dead).
// ---------------------------------------------------------------------------
__global__ __launch_bounds__(256) void wout_tr_kernel(const void* __restrict__ Wout,
                                                      ushort* __restrict__ woT,
                                                      const ushort* __restrict__ probe) {
    const bool ib = detect_bf16(probe);
    __shared__ ushort tile[32 * 33];
    do_transpose(Wout, woT, blockIdx.x, blockIdx.y, 1024, 512, ib, tile);
}

// ---------------------------------------------------------------------------
// LN2: input bf16, gamma + OUTPUT dtype detected.
// ---------------------------------------------------------------------------
__global__ __launch_bounds__(256) void ln2_kernel(const ushort* __restrict__ y,
                                                  const void* __restrict__ gin,
                                                  void* __restrict__ out,
                                                  const ushort* __restrict__ probe) {
    const bool ob = detect_bf16(probe);
    const int row = blockIdx.x;
    const int tid = threadIdx.x;

    uint2 u = *(const uint2*)(y + (size_t)row * 1024 + tid * 4);
    float v0 = scrub(bf2f((ushort)(u.x & 0xFFFF)), 1e8f);
    float v1 = scrub(bf2f((ushort)(u.x >> 16)),    1e8f);
    float v2 = scrub(bf2f((ushort)(u.y & 0xFFFF)), 1e8f);
    float v3 = scrub(bf2f((ushort)(u.y >> 16)),    1e8f);

    float g0, g1, g2, g3;
    if (ob) {
        uint2 gu = *(const uint2*)((const ushort*)gin + tid * 4);
        g0 = bf2f((ushort)(gu.x & 0xFFFF)); g1 = bf2f((ushort)(gu.x >> 16));
        g2 = bf2f((ushort)(gu.y & 0xFFFF)); g3 = bf2f((ushort)(gu.y >> 16));
    } else {
        float4 gv = *(const float4*)((const float*)gin + tid * 4);
        g0 = gv.x; g1 = gv.y; g2 = gv.z; g3 = gv.w;
    }
    g0 = scrub(g0, 1e8f); g1 = scrub(g1, 1e8f); g2 = scrub(g2, 1e8f); g3 = scrub(g3, 1e8f);

    float s  = v0 + v1 + v2 + v3;
    float sq = v0 * v0 + v1 * v1 + v2 * v2 + v3 * v3;
    #pragma unroll
    for (int off = 1; off < 64; off <<= 1) {
        s  += __shfl_xor(s, off);
        sq += __shfl_xor(sq, off);
    }
    __shared__ float red[8];
    const int w = tid >> 6, lane = tid & 63;
    if (lane == 0) { red[w] = s; red[w + 4] = sq; }
    __syncthreads();
    float S  = red[0] + red[1] + red[2] + red[3];
    float SQ = red[4] + red[5] + red[6] + red[7];

    float mean = S * (1.0f / 1024.0f);
    float var  = SQ * (1.0f / 1024.0f) - mean * mean;
    float rstd = rsqrtf(fmaxf(var, 0.0f) + 1e-5f);

    float o0 = (v0 - mean) * rstd * g0;
    float o1 = (v1 - mean) * rstd * g1;
    float o2 = (v2 - mean) * rstd * g2;
    float o3 = (v3 - mean) * rstd * g3;
    if (ob) {
        uint2 ov;
        ov.x = pk2(o0, o1);
        ov.y = pk2(o2, o3);
        *(uint2*)((ushort*)out + (size_t)row * 1024 + tid * 4) = ov;
    } else {
        *(float4*)((float*)out + (size_t)row * 1024 + tid * 4) = make_float4(o0, o1, o2, o3);
    }
}

// ---------------------------------------------------------------------------
// Fused QKV GEMM with global_load_lds staging.
// grid (10,128): bx<8 q (l2norm, pre-scaled by log2(e) for exp2 softmax),
// bx==8 k (l2norm -> SLAB layout), bx==9 v (-> SLAB layout).
//   K: kb[b][kblk32][d-oct8][pos32][e8], pos = bitswap23(key&31) (bakes the
//      in-register-P permutation into the layout).
//   V: vt[b][kblk32][k-oct4][d64][kk8].
// ---------------------------------------------------------------------------
__global__ __launch_bounds__(256) void gemm_qkv(const ushort* __restrict__ A,
                                                const ushort* __restrict__ Bt,
                                                ushort* __restrict__ qb,
                                                ushort* __restrict__ kb,
                                                ushort* __restrict__ vt) {
    __shared__ ushort a_t[64 * 32];
    __shared__ ushort b_t[64 * 32];

    const int bx = blockIdx.x;
    const int n0 = bx * 64, m0 = blockIdx.y * 64;
    const int tid = threadIdx.x;
    const int w = tid >> 6, lane = tid & 63;
    const int fm = lane & 15, quad = lane >> 4;
    const int K = 1024;

    // glds chunk map: thread t -> row t>>2 (0..63), k-octet t&3
    const ushort* ag = A + (size_t)(m0 + (tid >> 2)) * K + (tid & 3) * 8;
    const ushort* bg = Bt + (size_t)(n0 + (tid >> 2)) * K + (tid & 3) * 8;
    ushort* la = a_t + w * 512;   // wave-uniform LDS base
    ushort* lb = b_t + w * 512;

    floatx4 acc[4];
    floatx4 zero4 = {0.0f, 0.0f, 0.0f, 0.0f};
    #pragma unroll
    for (int nt = 0; nt < 4; nt++) acc[nt] = zero4;

    union U8 { uint4 u4; short8 s8; };

    for (int k0 = 0; k0 < K; k0 += 32) {
        __syncthreads();                   // prior iter's frag reads done
        glds16(ag + k0, la);
        glds16(bg + k0, lb);
        __syncthreads();                   // vmcnt drained before reads

        U8 af;
        af.u4 = *(const uint4*)&a_t[(w * 16 + fm) * 32 + quad * 8];
        #pragma unroll
        for (int nt = 0; nt < 4; nt++) {
            U8 bf;
            bf.u4 = *(const uint4*)&b_t[(nt * 16 + fm) * 32 + quad * 8];
            acc[nt] = __builtin_amdgcn_mfma_f32_16x16x32_bf16(af.s8, bf.s8, acc[nt], 0, 0, 0);
        }
    }

    if (bx < 9) {
        // q gets 4*log2(e) so attn's QK accumulates S*log2e -> bare exp2.
        const float qsc = (bx < 8) ? 5.7707801636f : 4.0f;
        float sc[4];
        #pragma unroll
        for (int r = 0; r < 4; r++) {
            float ss = acc[0][r] * acc[0][r] + acc[1][r] * acc[1][r]
                     + acc[2][r] * acc[2][r] + acc[3][r] * acc[3][r];
            ss += __shfl_xor(ss, 1);
            ss += __shfl_xor(ss, 2);
            ss += __shfl_xor(ss, 4);
            ss += __shfl_xor(ss, 8);
            sc[r] = qsc / fmaxf(sqrtf(ss), 1e-12f);
        }
        if (bx < 8) {
            ushort* op = qb + n0;
            #pragma unroll
            for (int nt = 0; nt < 4; nt++)
                #pragma unroll
                for (int r = 0; r < 4; r++)
                    op[(size_t)(m0 + w * 16 + quad * 4 + r) * 512 + nt * 16 + fm] =
                        f2bf(acc[nt][r] * sc[r]);
        } else {
            // K slab write: key = m0 + w*16 + quad*4 + r, d = nt*16 + fm.
            // idx = bb*131072 + kblk*2048 + (d>>3)*256 + bitswap23(key&31)*8 + (d&7)
            const int bb = m0 >> 11;
            const int kblk = ((m0 & 2047) >> 5) + (w >> 1);
            const int qsw = ((quad & 1) << 1) | (quad >> 1);   // bitswap23 of quad
            ushort* op = kb + (size_t)bb * 131072 + kblk * 2048
                       + (w & 1) * 128 + qsw * 32 + (fm & 7);
            #pragma unroll
            for (int nt = 0; nt < 4; nt++) {
                const int oct = nt * 2 + (fm >> 3);
                #pragma unroll
                for (int r = 0; r < 4; r++)
                    op[oct * 256 + r * 8] = f2bf(acc[nt][r] * sc[r]);
            }
        }
    } else {
        // V slab write: key = m0 + w*16 + quad*4 + r, d = nt*16 + fm.
        // idx = bb*131072 + kblk*2048 + ((key>>3)&3)*512 + d*8 + (key&7)
        const int bb = m0 >> 11;
        const int kblk = ((m0 & 2047) >> 5) + (w >> 1);
        const int koct = ((w & 1) * 2 + (quad >> 1)) & 3;
        ushort* vb = vt + (size_t)bb * 131072 + kblk * 2048 + koct * 512 + (quad & 1) * 4;
        #pragma unroll
        for (int nt = 0; nt < 4; nt++) {
            uint2 pv;
            pv.x = pk2(acc[nt][0], acc[nt][1]);
            pv.y = pk2(acc[nt][2], acc[nt][3]);
            *(uint2*)(vb + (nt * 16 + fm) * 8) = pv;
        }
    }
}

// ---------------------------------------------------------------------------
// Out-projection GEMM, m97-style: 128x128 tile, BK=32, global_load_lds w=16.
// ---------------------------------------------------------------------------
__global__ __launch_bounds__(256) void gemm_bt128(const ushort* __restrict__ A,
                                                  const ushort* __restrict__ Bt,
                                                  ushort* __restrict__ C,
                                                  int M, int N, int K) {
    __shared__ ushort a_t[128][32];
    __shared__ ushort b_t[128][32];

    const int n0 = blockIdx.x * 128, m0 = blockIdx.y * 128;
    const int tid = threadIdx.x;
    const int w = tid >> 6, lane = tid & 63;
    const int fm = lane & 15, quad = lane >> 4;

    const int c0 = tid, c1 = tid + 256;
    const ushort* ag0 = A + (size_t)(m0 + (c0 >> 2)) * K + (c0 & 3) * 8;
    const ushort* ag1 = A + (size_t)(m0 + (c1 >> 2)) * K + (c1 & 3) * 8;
    const ushort* bg0 = Bt + (size_t)(n0 + (c0 >> 2)) * K + (c0 & 3) * 8;
    const ushort* bg1 = Bt + (size_t)(n0 + (c1 >> 2)) * K + (c1 & 3) * 8;
    ushort* la0 = &a_t[0][0] + w * 512;
    ushort* la1 = &a_t[0][0] + 2048 + w * 512;
    ushort* lb0 = &b_t[0][0] + w * 512;
    ushort* lb1 = &b_t[0][0] + 2048 + w * 512;

    floatx4 acc[2][8];
    floatx4 zero4 = {0.0f, 0.0f, 0.0f, 0.0f};
    #pragma unroll
    for (int mt = 0; mt < 2; mt++)
        #pragma unroll
        for (int nt = 0; nt < 8; nt++) acc[mt][nt] = zero4;

    union U8 { uint4 u4; short8 s8; };

    for (int k0 = 0; k0 < K; k0 += 32) {
        __syncthreads();
        glds16(ag0 + k0, la0);
        glds16(ag1 + k0, la1);
        glds16(bg0 + k0, lb0);
        glds16(bg1 + k0, lb1);
        __syncthreads();

        U8 af[2];
        #pragma unroll
        for (int mt = 0; mt < 2; mt++)
            af[mt].u4 = *(const uint4*)&a_t[w * 32 + mt * 16 + fm][quad * 8];
        #pragma unroll
        for (int nt = 0; nt < 8; nt++) {
            U8 bf;
            bf.u4 = *(const uint4*)&b_t[nt * 16 + fm][quad * 8];
            acc[0][nt] = __builtin_amdgcn_mfma_f32_16x16x32_bf16(af[0].s8, bf.s8, acc[0][nt], 0, 0, 0);
            acc[1][nt] = __builtin_amdgcn_mfma_f32_16x16x32_bf16(af[1].s8, bf.s8, acc[1][nt], 0, 0, 0);
        }
    }

    #pragma unroll
    for (int mt = 0; mt < 2; mt++)
        #pragma unroll
        for (int nt = 0; nt < 8; nt++)
            #pragma unroll
            for (int r = 0; r < 4; r++)
                C[(size_t)(m0 + w * 32 + mt * 16 + quad * 4 + r) * N + n0 + nt * 16 + fm] =
                    f2bf(acc[mt][nt][r]);
}

// ---------------------------------------------------------------------------
// Flash attention v7: v6 structure + SOFTWARE-PIPELINED SOFTMAX.
//
// r7 post-mortem: step wall (4000 cyc/CU) == MFMA burst (1024) + VALU burst
// (1480) + LDS burst (1536) EXACTLY — phases are serial because each wave's
// step is a strict chain QK->exp->PV and all waves run it in lockstep.
// v7 breaks the chain: interval s computes QK(s) + exp(s) -> P(s) in regs,
// and PV(s-1) with LAST interval's P. QK(s), PV(s-1), exp(s) are mutually
// independent -> compiler interleaves MFMA/VALU/LDS; bursts overlap.
// V is staged one step behind K (V(s) staged in interval s, read in s+1),
// so plain double-buffering still works with no extra LDS.
// Static P names (pA/pB) via 2-unrolled loop (no runtime-indexed regs).
// All layouts, math, split-K combine: unchanged (validated r5-r7).
// LDS: staging 32KB + combine 34.8KB (reused). 2 blocks/CU, 16 waves/CU.
// ---------------------------------------------------------------------------
__global__ __launch_bounds__(512, 4) void attn_kernel(const ushort* __restrict__ q,
                                                      const ushort* __restrict__ kb,
                                                      const ushort* __restrict__ vt,
                                                      ushort* __restrict__ out) {
    __shared__ ushort smem[17408];          // 34.8 KB
    ushort* k_t = smem;                     // [ks][buf][oct8][pos32][8]
    ushort* v_t = smem + 8192;              // [ks][buf][oct4][d64][8]

    const int i0 = blockIdx.x * 128;
    const int h0 = blockIdx.y, b = blockIdx.z;
    const int tid = threadIdx.x, w = tid >> 6, lane = tid & 63;
    const int qg = w & 3;          // query group of 32 (0..3)
    const int ks = w >> 2;         // key half: 0 -> [0,1024), 1 -> [1024,2048)
    const int cq = lane & 31;      // C col = query; A row = position / d
    const int hi = lane >> 5;      // k-slice half within fragment

    union U8 { uint4 u4; short8 s8; };

    // Q B-frags: qf[dm] holds Q[q=cq][d = 16*dm + 8*hi + j]
    const ushort* qbase = q + (size_t)(b * 2048 + i0 + qg * 32 + cq) * 512 + h0 * 64 + hi * 8;
    U8 qf[4];
    #pragma unroll
    for (int dm = 0; dm < 4; dm++) qf[dm].u4 = *(const uint4*)(qbase + dm * 16);

    floatx16 acc0, acc1;           // O^T partials: d 0..31 (acc0), 32..63 (acc1)
    #pragma unroll
    for (int i = 0; i < 16; i++) { acc0[i] = 0.0f; acc1[i] = 0.0f; }
    float lsum = 0.0f;

    // Contiguous slab sources: K/V pre-formatted by gemm_qkv.
    const ushort* kSrc = kb + (size_t)b * 131072 + ks * 65536 + lane * 8;
    const ushort* vSrc = vt + (size_t)b * 131072 + ks * 65536 + lane * 8;

    ushort* kT = k_t + ks * 4096;
    ushort* vT = v_t + ks * 4096;

    auto stageK = [&](int s, int buf) {
        glds16(kSrc + s * 2048 + qg * 512, kT + buf * 2048 + qg * 512);
    };
    auto stageV = [&](int s, int buf) {
        glds16(vSrc + s * 2048 + qg * 512, vT + buf * 2048 + qg * 512);
    };

    // QK^T + exp2 + pack -> P (key-permuted in layout)
    auto qk_exp = [&](int buf, U8& pb0, U8& pb1) {
        const int bo = buf * 2048;
        floatx16 st;
        #pragma unroll
        for (int i = 0; i < 16; i++) st[i] = -23.0831206f;   // -16*log2(e)
        #pragma unroll
        for (int dm = 0; dm < 4; dm++) {
            U8 kf;
            kf.u4 = *(const uint4*)&kT[bo + (2 * dm + hi) * 256 + cq * 8];
            st = __builtin_amdgcn_mfma_f32_32x32x16_bf16(kf.s8, qf[dm].s8, st, 0, 0, 0);
        }
        float p_[16];
        #pragma unroll
        for (int r = 0; r < 16; r++) p_[r] = __builtin_amdgcn_exp2f(st[r]);
        lsum += (((p_[0] + p_[1]) + (p_[2] + p_[3])) + ((p_[4] + p_[5]) + (p_[6] + p_[7])))
              + (((p_[8] + p_[9]) + (p_[10] + p_[11])) + ((p_[12] + p_[13]) + (p_[14] + p_[15])));
        pb0.u4.x = pk2(p_[0], p_[1]);   pb0.u4.y = pk2(p_[2], p_[3]);
        pb0.u4.z = pk2(p_[4], p_[5]);   pb0.u4.w = pk2(p_[6], p_[7]);
        pb1.u4.x = pk2(p_[8], p_[9]);   pb1.u4.y = pk2(p_[10], p_[11]);
        pb1.u4.z = pk2(p_[12], p_[13]); pb1.u4.w = pk2(p_[14], p_[15]);
    };

    // PV: O^T(d-tile) += V^T(key-slice) x P^T
    auto pv = [&](int buf, U8 pb0, U8 pb1) {
        const int bo = buf * 2048;
        U8 vf;
        vf.u4 = *(const uint4*)&vT[bo + (0 + hi) * 512 + cq * 8];
        acc0 = __builtin_amdgcn_mfma_f32_32x32x16_bf16(vf.s8, pb0.s8, acc0, 0, 0, 0);
        vf.u4 = *(const uint4*)&vT[bo + (2 + hi) * 512 + cq * 8];
        acc0 = __builtin_amdgcn_mfma_f32_32x32x16_bf16(vf.s8, pb1.s8, acc0, 0, 0, 0);
        vf.u4 = *(const uint4*)&vT[bo + (0 + hi) * 512 + (32 + cq) * 8];
        acc1 = __builtin_amdgcn_mfma_f32_32x32x16_bf16(vf.s8, pb0.s8, acc1, 0, 0, 0);
        vf.u4 = *(const uint4*)&vT[bo + (2 + hi) * 512 + (32 + cq) * 8];
        acc1 = __builtin_amdgcn_mfma_f32_32x32x16_bf16(vf.s8, pb1.s8, acc1, 0, 0, 0);
    };

    U8 pA0, pA1, pB0, pB1;         // P for even / odd steps (static names)

    // prologue: K(0) -> Kbuf0
    stageK(0, 0);
    __syncthreads();

    // interval 0: stage K(1), V(0); QK(0)->pA
    stageK(1, 1);
    stageV(0, 0);
    qk_exp(0, pA0, pA1);
    __syncthreads();

    // intervals 1..31, unrolled by 2 (odd s -> pB, even s -> pA)
    for (int s = 1; s < 32; s += 2) {
        // odd interval s: K in buf1, stage K(s+1)->buf0, V(s)->buf1; PV(s-1) from Vbuf0
        if (s + 1 < 32) stageK(s + 1, 0);
        stageV(s, 1);
        qk_exp(1, pB0, pB1);
        pv(0, pA0, pA1);
        __syncthreads();

        if (s + 1 < 32) {
            // even interval s+1: K in buf0, stage K(s+2)->buf1, V(s+1)->buf0; PV(s) from Vbuf1
            if (s + 2 < 32) stageK(s + 2, 1);
            stageV(s + 1, 0);
            qk_exp(0, pA0, pA1);
            pv(1, pB0, pB1);
            __syncthreads();
        }
    }
    // epilogue: PV(31) (odd -> pB, Vbuf1; staged in interval 31, synced)
    pv(1, pB0, pB1);
    __syncthreads();               // all LDS reads done before combine overwrites

    // ---- split-K combine via LDS (stride-34 f32) ----
    float* row = (float*)smem + (qg * 64 + lane) * 34;
    if (ks == 1) {
        #pragma unroll
        for (int i = 0; i < 16; i++) { row[i] = acc0[i]; row[16 + i] = acc1[i]; }
        row[32] = lsum;
    }
    __syncthreads();
    if (ks == 1) return;
    #pragma unroll
    for (int i = 0; i < 16; i++) { acc0[i] += row[i]; acc1[i] += row[16 + i]; }
    lsum += row[32];
    lsum += __shfl_xor(lsum, 32);   // combine hi/lo position halves
    float li = 1.0f / fmaxf(lsum, 1e-30f);

    // write out: reg 4t+u of acc0 -> d = u + 8t + 4hi; acc1 -> +32
    ushort* ob = out + (size_t)(b * 2048 + i0 + qg * 32 + cq) * 512 + h0 * 64 + hi * 4;
    #pragma unroll
    for (int t = 0; t < 4; t++) {
        uint2 ov;
        ov.x = pk2(acc0[4 * t] * li, acc0[4 * t + 1] * li);
        ov.y = pk2(acc0[4 * t + 2] * li, acc0[4 * t + 3] * li);
        *(uint2*)(ob + t * 8) = ov;
        ov.x = pk2(acc1[4 * t] * li, acc1[4 * t + 1] * li);
        ov.y = pk2(acc1[4 * t + 2] * li, acc1[4 * t + 3] * li);
        *(uint2*)(ob + 32 + t * 8) = ov;
    }
}

// ---------------------------------------------------------------------------
// Memory plan (bf16 intermediates, ws_size needed = 16MB):
//   d_out: xn [0:16MB) (dead after gemm_qkv) -> ao [0:8MB), woT [8:16MB)
//   ws:    qb [0:8), kb [8:9), vt [9:11), wcatT [11:12.25); y [0:16) after attn.
// Dispatches (6): prep, gemm_qkv, wout_tr, attn, gemm_bt128, ln2.
// ---------------------------------------------------------------------------
extern "C" void kernel_launch(void* const* d_in, const int* in_sizes, int n_in,
                              void* d_out, int out_size, void* d_ws, size_t ws_size,
                              hipStream_t stream) {
    const void* x          = d_in[0];
    const void* norm_g     = d_in[1];
    const void* Wq         = d_in[2];
    const void* Wkv        = d_in[3];
    const void* Wout       = d_in[4];
    const void* out_norm_g = d_in[5];
    const ushort* probe = (const ushort*)d_in[0];
    ushort* ws = (ushort*)d_ws;

    const size_t M1 = 1024 * 1024 / 2;  // bf16 elems per MB
    ushort* xn    = (ushort*)d_out;
    ushort* ao    = (ushort*)d_out;
    ushort* woT   = (ushort*)((char*)d_out + (8u << 20));
    ushort* qb    = ws;
    ushort* kb    = ws + 8 * M1;
    ushort* vt    = ws + 9 * M1;
    ushort* wcatT = ws + 11 * M1;
    ushort* y     = ws;

    // prep: LN1 + Wq^T + Wkv^T fused
    prep_kernel<<<8832, 256, 0, stream>>>(x, norm_g, Wq, Wkv, xn, wcatT, probe);

    // fused q/k/v projection + l2norm + K/V slab formatting
    gemm_qkv<<<dim3(10, 128), 256, 0, stream>>>(xn, wcatT, qb, kb, vt);

    // Wout^T -> d_out[8:16MB) (xn dead now)
    wout_tr_kernel<<<dim3(32, 16), 256, 0, stream>>>(Wout, woT, probe);

    // attention -> ao
    attn_kernel<<<dim3(16, 8, 4), 512, 0, stream>>>(qb, kb, vt, ao);

    // y = ao @ Wout  (128-tile, global_load_lds)
    gemm_bt128<<<dim3(8, 64), 256, 0, stream>>>(ao, woT, y, 8192, 1024, 512);

    // LN2: y -> final output
    ln2_kernel<<<8192, 256, 0, stream>>>(y, out_norm_g, d_out, probe);
}

// Round 10
// 203.472 us; speedup vs baseline: 1.1156x; 1.0133x over previous
//
#include <hip/hip_runtime.h>
#include <hip/hip_bf16.h>

typedef __attribute__((ext_vector_type(8))) short short8;
typedef __attribute__((ext_vector_type(4))) float floatx4;
typedef __attribute__((ext_vector_type(16))) float floatx16;

__device__ __forceinline__ float bf2f(ushort u) {
    return __uint_as_float(((unsigned int)u) << 16);
}
__device__ __forceinline__ ushort f2bf(float f) {
    unsigned int u = __float_as_uint(f);
    unsigned int r = (u + 0x7FFFu + ((u >> 16) & 1u)) >> 16;
    return (ushort)r;
}
// packed f32x2 -> bf16x2
__device__ __forceinline__ unsigned int pk2(float a, float b) {
    union { __hip_bfloat162 h; unsigned int u; } cv;
    cv.h = __float22bfloat162_rn(make_float2(a, b));
    return cv.u;
}
__device__ __forceinline__ float scrub(float v, float lim) {
    return fminf(fmaxf(v, -lim), lim);
}
// async global->LDS, 16B per lane (lane i lands at wave-uniform lds base + 16*i)
__device__ __forceinline__ void glds16(const ushort* g, ushort* l) {
    __builtin_amdgcn_global_load_lds((const __attribute__((address_space(1))) void*)g,
                                     (__attribute__((address_space(3))) void*)l, 16, 0, 0);
}

// Wave-uniform dtype probe on x: bf16 N(0,1) data has exponent byte in [117,131]
// ~99% at even ushort indices; fp32-as-ushort gives ~6%. 32 samples, thr 16.
__device__ __forceinline__ bool detect_bf16(const ushort* __restrict__ probe) {
    const int lane = threadIdx.x & 63;
    ushort u = probe[(lane & 31) * 2];
    int e = (u >> 7) & 0xFF;
    bool pl = (e >= 117) && (e <= 131) && (lane < 32);
    return __popcll(__ballot(pl)) >= 16;
}

// ---------------------------------------------------------------------------
// Transpose helper (256 threads).
// ---------------------------------------------------------------------------
__device__ __forceinline__ void do_transpose(const void* __restrict__ in,
                                             ushort* __restrict__ out,
                                             int bx, int by, int in_rs, int out_rs,
                                             bool ib, ushort* tile /*32x33*/) {
    const int tx = threadIdx.x & 31, ty = threadIdx.x >> 5;
    #pragma unroll
    for (int rr = 0; rr < 32; rr += 8) {
        size_t idx = (size_t)(by * 32 + ty + rr) * in_rs + bx * 32 + tx;
        float v = ib ? bf2f(((const ushort*)in)[idx]) : ((const float*)in)[idx];
        tile[(ty + rr) * 33 + tx] = f2bf(scrub(v, 1e8f));
    }
    __syncthreads();
    #pragma unroll
    for (int rr = 0; rr < 32; rr += 8) {
        int r = bx * 32 + ty + rr;
        int c = by * 32 + tx;
        out[(size_t)r * out_rs + c] = tile[tx * 33 + (ty + rr)];
    }
}

// ---------------------------------------------------------------------------
// prep: fused LN1 (blocks 0..8191) + Wq^T (8192..8703) + Wkv^T (8704..8831).
// ---------------------------------------------------------------------------
__global__ __launch_bounds__(256) void prep_kernel(const void* __restrict__ xin,
                                                   const void* __restrict__ gin,
                                                   const void* __restrict__ Wq,
                                                   const void* __restrict__ Wkv,
                                                   ushort* __restrict__ xn,
                                                   ushort* __restrict__ wcatT,
                                                   const ushort* __restrict__ probe) {
    const bool ib = detect_bf16(probe);
    const int id = blockIdx.x;
    __shared__ ushort tile[32 * 33];
    __shared__ float red[8];

    if (id >= 8192) {
        if (id < 8704) {
            int t = id - 8192;                  // Wq[1024][512] -> wcatT[0:512)[1024]
            do_transpose(Wq, wcatT, t & 15, t >> 4, 512, 1024, ib, tile);
        } else {
            int t = id - 8704;                  // Wkv[1024][128] -> wcatT[512:640)[1024]
            do_transpose(Wkv, wcatT + (size_t)512 * 1024, t & 3, t >> 2, 128, 1024, ib, tile);
        }
        return;
    }

    const int row = id;
    const int tid = threadIdx.x;
    float v0, v1, v2, v3, g0, g1, g2, g3;
    if (ib) {
        uint2 u = *(const uint2*)((const ushort*)xin + (size_t)row * 1024 + tid * 4);
        v0 = bf2f((ushort)(u.x & 0xFFFF)); v1 = bf2f((ushort)(u.x >> 16));
        v2 = bf2f((ushort)(u.y & 0xFFFF)); v3 = bf2f((ushort)(u.y >> 16));
        uint2 gu = *(const uint2*)((const ushort*)gin + tid * 4);
        g0 = bf2f((ushort)(gu.x & 0xFFFF)); g1 = bf2f((ushort)(gu.x >> 16));
        g2 = bf2f((ushort)(gu.y & 0xFFFF)); g3 = bf2f((ushort)(gu.y >> 16));
    } else {
        float4 xv = *(const float4*)((const float*)xin + (size_t)row * 1024 + tid * 4);
        v0 = xv.x; v1 = xv.y; v2 = xv.z; v3 = xv.w;
        float4 gv = *(const float4*)((const float*)gin + tid * 4);
        g0 = gv.x; g1 = gv.y; g2 = gv.z; g3 = gv.w;
    }
    v0 = scrub(v0, 1e8f); v1 = scrub(v1, 1e8f); v2 = scrub(v2, 1e8f); v3 = scrub(v3, 1e8f);
    g0 = scrub(g0, 1e8f); g1 = scrub(g1, 1e8f); g2 = scrub(g2, 1e8f); g3 = scrub(g3, 1e8f);

    float s  = v0 + v1 + v2 + v3;
    float sq = v0 * v0 + v1 * v1 + v2 * v2 + v3 * v3;
    #pragma unroll
    for (int off = 1; off < 64; off <<= 1) {
        s  += __shfl_xor(s, off);
        sq += __shfl_xor(sq, off);
    }
    const int w = tid >> 6, lane = tid & 63;
    if (lane == 0) { red[w] = s; red[w + 4] = sq; }
    __syncthreads();
    float S  = red[0] + red[1] + red[2] + red[3];
    float SQ = red[4] + red[5] + red[6] + red[7];

    float mean = S * (1.0f / 1024.0f);
    float var  = SQ * (1.0f / 1024.0f) - mean * mean;
    float rstd = rsqrtf(fmaxf(var, 0.0f) + 1e-5f);

    uint2 ov;
    ov.x = pk2((v0 - mean) * rstd * g0, (v1 - mean) * rstd * g1);
    ov.y = pk2((v2 - mean) * rstd * g2, (v3 - mean) * rstd * g3);
    *(uint2*)(xn + (size_t)row * 1024 + tid * 4) = ov;
}

// ---------------------------------------------------------------------------
// Standalone Wout transpose (runs after gemm_qkv, xn dead).
// ---------------------------------------------------------------------------
__global__ __launch_bounds__(256) void wout_tr_kernel(const void* __restrict__ Wout,
                                                      ushort* __restrict__ woT,
                                                      const ushort* __restrict__ probe) {
    const bool ib = detect_bf16(probe);
    __shared__ ushort tile[32 * 33];
    do_transpose(Wout, woT, blockIdx.x, blockIdx.y, 1024, 512, ib, tile);
}

// ---------------------------------------------------------------------------
// LN2: input bf16, gamma + OUTPUT dtype detected.
// ---------------------------------------------------------------------------
__global__ __launch_bounds__(256) void ln2_kernel(const ushort* __restrict__ y,
                                                  const void* __restrict__ gin,
                                                  void* __restrict__ out,
                                                  const ushort* __restrict__ probe) {
    const bool ob = detect_bf16(probe);
    const int row = blockIdx.x;
    const int tid = threadIdx.x;

    uint2 u = *(const uint2*)(y + (size_t)row * 1024 + tid * 4);
    float v0 = scrub(bf2f((ushort)(u.x & 0xFFFF)), 1e8f);
    float v1 = scrub(bf2f((ushort)(u.x >> 16)),    1e8f);
    float v2 = scrub(bf2f((ushort)(u.y & 0xFFFF)), 1e8f);
    float v3 = scrub(bf2f((ushort)(u.y >> 16)),    1e8f);

    float g0, g1, g2, g3;
    if (ob) {
        uint2 gu = *(const uint2*)((const ushort*)gin + tid * 4);
        g0 = bf2f((ushort)(gu.x & 0xFFFF)); g1 = bf2f((ushort)(gu.x >> 16));
        g2 = bf2f((ushort)(gu.y & 0xFFFF)); g3 = bf2f((ushort)(gu.y >> 16));
    } else {
        float4 gv = *(const float4*)((const float*)gin + tid * 4);
        g0 = gv.x; g1 = gv.y; g2 = gv.z; g3 = gv.w;
    }
    g0 = scrub(g0, 1e8f); g1 = scrub(g1, 1e8f); g2 = scrub(g2, 1e8f); g3 = scrub(g3, 1e8f);

    float s  = v0 + v1 + v2 + v3;
    float sq = v0 * v0 + v1 * v1 + v2 * v2 + v3 * v3;
    #pragma unroll
    for (int off = 1; off < 64; off <<= 1) {
        s  += __shfl_xor(s, off);
        sq += __shfl_xor(sq, off);
    }
    __shared__ float red[8];
    const int w = tid >> 6, lane = tid & 63;
    if (lane == 0) { red[w] = s; red[w + 4] = sq; }
    __syncthreads();
    float S  = red[0] + red[1] + red[2] + red[3];
    float SQ = red[4] + red[5] + red[6] + red[7];

    float mean = S * (1.0f / 1024.0f);
    float var  = SQ * (1.0f / 1024.0f) - mean * mean;
    float rstd = rsqrtf(fmaxf(var, 0.0f) + 1e-5f);

    float o0 = (v0 - mean) * rstd * g0;
    float o1 = (v1 - mean) * rstd * g1;
    float o2 = (v2 - mean) * rstd * g2;
    float o3 = (v3 - mean) * rstd * g3;
    if (ob) {
        uint2 ov;
        ov.x = pk2(o0, o1);
        ov.y = pk2(o2, o3);
        *(uint2*)((ushort*)out + (size_t)row * 1024 + tid * 4) = ov;
    } else {
        *(float4*)((float*)out + (size_t)row * 1024 + tid * 4) = make_float4(o0, o1, o2, o3);
    }
}

// ---------------------------------------------------------------------------
// Fused QKV GEMM, r9: 128x128 m97-style tile (2.65x per-FLOP vs 64-tile on
// the m90->m97 ladder). grid (5,64) = 320 blocks, 256 thr.
//   bx<4 : q tiles (cols n0..n0+127 = heads 2bx, 2bx+1) -> per-head l2norm,
//          scaled by 4*log2(e) for attn's exp2 softmax.
//   bx==4: cols 512..639 -> nt 0-3 = k (l2norm, scale 4, SLAB layout),
//          nt 4-7 = v (SLAB layout). One wave covers exactly one 32-key
//          block (rows m0+w*32..+31) -> slab formulas from r5 carry over
//          with pos = mt*16 + qsw*4 + r.
// Slabs (validated r5-r8):
//   K: kb[b][kblk32][d-oct8][pos32][e8], pos = bitswap23(key&31)
//   V: vt[b][kblk32][k-oct4][d64][kk8]
// ---------------------------------------------------------------------------
__global__ __launch_bounds__(256) void gemm_qkv128(const ushort* __restrict__ A,
                                                   const ushort* __restrict__ Bt,
                                                   ushort* __restrict__ qb,
                                                   ushort* __restrict__ kb,
                                                   ushort* __restrict__ vt) {
    __shared__ ushort a_t[128][32];
    __shared__ ushort b_t[128][32];

    const int bx = blockIdx.x;
    const int n0 = bx * 128, m0 = blockIdx.y * 128;
    const int tid = threadIdx.x;
    const int w = tid >> 6, lane = tid & 63;
    const int fm = lane & 15, quad = lane >> 4;
    const int K = 1024;

    const int c0 = tid, c1 = tid + 256;
    const ushort* ag0 = A + (size_t)(m0 + (c0 >> 2)) * K + (c0 & 3) * 8;
    const ushort* ag1 = A + (size_t)(m0 + (c1 >> 2)) * K + (c1 & 3) * 8;
    const ushort* bg0 = Bt + (size_t)(n0 + (c0 >> 2)) * K + (c0 & 3) * 8;
    const ushort* bg1 = Bt + (size_t)(n0 + (c1 >> 2)) * K + (c1 & 3) * 8;
    ushort* la0 = &a_t[0][0] + w * 512;
    ushort* la1 = &a_t[0][0] + 2048 + w * 512;
    ushort* lb0 = &b_t[0][0] + w * 512;
    ushort* lb1 = &b_t[0][0] + 2048 + w * 512;

    floatx4 acc[2][8];
    floatx4 zero4 = {0.0f, 0.0f, 0.0f, 0.0f};
    #pragma unroll
    for (int mt = 0; mt < 2; mt++)
        #pragma unroll
        for (int nt = 0; nt < 8; nt++) acc[mt][nt] = zero4;

    union U8 { uint4 u4; short8 s8; };

    for (int k0 = 0; k0 < K; k0 += 32) {
        __syncthreads();
        glds16(ag0 + k0, la0);
        glds16(ag1 + k0, la1);
        glds16(bg0 + k0, lb0);
        glds16(bg1 + k0, lb1);
        __syncthreads();

        U8 af[2];
        #pragma unroll
        for (int mt = 0; mt < 2; mt++)
            af[mt].u4 = *(const uint4*)&a_t[w * 32 + mt * 16 + fm][quad * 8];
        #pragma unroll
        for (int nt = 0; nt < 8; nt++) {
            U8 bf;
            bf.u4 = *(const uint4*)&b_t[nt * 16 + fm][quad * 8];
            acc[0][nt] = __builtin_amdgcn_mfma_f32_16x16x32_bf16(af[0].s8, bf.s8, acc[0][nt], 0, 0, 0);
            acc[1][nt] = __builtin_amdgcn_mfma_f32_16x16x32_bf16(af[1].s8, bf.s8, acc[1][nt], 0, 0, 0);
        }
    }

    if (bx < 4) {
        // q epilogue: two heads per tile; per-row l2norm over each head's 64 cols.
        const float qsc = 5.7707801636f;       // 4*log2(e)
        #pragma unroll
        for (int mt = 0; mt < 2; mt++) {
            float scA[4], scB[4];
            #pragma unroll
            for (int r = 0; r < 4; r++) {
                float sa = acc[mt][0][r] * acc[mt][0][r] + acc[mt][1][r] * acc[mt][1][r]
                         + acc[mt][2][r] * acc[mt][2][r] + acc[mt][3][r] * acc[mt][3][r];
                float sb = acc[mt][4][r] * acc[mt][4][r] + acc[mt][5][r] * acc[mt][5][r]
                         + acc[mt][6][r] * acc[mt][6][r] + acc[mt][7][r] * acc[mt][7][r];
                sa += __shfl_xor(sa, 1); sb += __shfl_xor(sb, 1);
                sa += __shfl_xor(sa, 2); sb += __shfl_xor(sb, 2);
                sa += __shfl_xor(sa, 4); sb += __shfl_xor(sb, 4);
                sa += __shfl_xor(sa, 8); sb += __shfl_xor(sb, 8);
                scA[r] = qsc / fmaxf(sqrtf(sa), 1e-12f);
                scB[r] = qsc / fmaxf(sqrtf(sb), 1e-12f);
            }
            #pragma unroll
            for (int nt = 0; nt < 8; nt++)
                #pragma unroll
                for (int r = 0; r < 4; r++)
                    qb[(size_t)(m0 + w * 32 + mt * 16 + quad * 4 + r) * 512 + n0 + nt * 16 + fm] =
                        f2bf(acc[mt][nt][r] * ((nt < 4) ? scA[r] : scB[r]));
        }
    } else {
        // k (nt 0-3) + v (nt 4-7) slab epilogue. One wave = one 32-key block.
        const int bb = m0 >> 11;                         // m0+w*32 stays in-batch
        const int kblk = ((m0 & 2047) >> 5) + w;
        const int qsw = ((quad & 1) << 1) | (quad >> 1); // bitswap23 of quad
        #pragma unroll
        for (int mt = 0; mt < 2; mt++) {
            // --- k: l2norm (scale 4) + slab write ---
            float sck[4];
            #pragma unroll
            for (int r = 0; r < 4; r++) {
                float ss = acc[mt][0][r] * acc[mt][0][r] + acc[mt][1][r] * acc[mt][1][r]
                         + acc[mt][2][r] * acc[mt][2][r] + acc[mt][3][r] * acc[mt][3][r];
                ss += __shfl_xor(ss, 1);
                ss += __shfl_xor(ss, 2);
                ss += __shfl_xor(ss, 4);
                ss += __shfl_xor(ss, 8);
                sck[r] = 4.0f / fmaxf(sqrtf(ss), 1e-12f);
            }
            // pos = mt*16 + qsw*4 + r -> elem offset pos*8
            ushort* kop = kb + (size_t)bb * 131072 + kblk * 2048
                        + mt * 128 + qsw * 32 + (fm & 7);
            #pragma unroll
            for (int nt = 0; nt < 4; nt++) {
                const int oct = nt * 2 + (fm >> 3);      // d = nt*16 + fm
                #pragma unroll
                for (int r = 0; r < 4; r++)
                    kop[oct * 256 + r * 8] = f2bf(acc[mt][nt][r] * sck[r]);
            }
            // --- v: slab write (d = (nt-4)*16 + fm) ---
            const int koct = mt * 2 + (quad >> 1);
            ushort* vb = vt + (size_t)bb * 131072 + kblk * 2048 + koct * 512 + (quad & 1) * 4;
            #pragma unroll
            for (int nt = 4; nt < 8; nt++) {
                uint2 pv;
                pv.x = pk2(acc[mt][nt][0], acc[mt][nt][1]);
                pv.y = pk2(acc[mt][nt][2], acc[mt][nt][3]);
                *(uint2*)(vb + ((nt - 4) * 16 + fm) * 8) = pv;
            }
        }
    }
}

// ---------------------------------------------------------------------------
// Out-projection GEMM, m97-style: 128x128 tile, BK=32, global_load_lds w=16.
// ---------------------------------------------------------------------------
__global__ __launch_bounds__(256) void gemm_bt128(const ushort* __restrict__ A,
                                                  const ushort* __restrict__ Bt,
                                                  ushort* __restrict__ C,
                                                  int M, int N, int K) {
    __shared__ ushort a_t[128][32];
    __shared__ ushort b_t[128][32];

    const int n0 = blockIdx.x * 128, m0 = blockIdx.y * 128;
    const int tid = threadIdx.x;
    const int w = tid >> 6, lane = tid & 63;
    const int fm = lane & 15, quad = lane >> 4;

    const int c0 = tid, c1 = tid + 256;
    const ushort* ag0 = A + (size_t)(m0 + (c0 >> 2)) * K + (c0 & 3) * 8;
    const ushort* ag1 = A + (size_t)(m0 + (c1 >> 2)) * K + (c1 & 3) * 8;
    const ushort* bg0 = Bt + (size_t)(n0 + (c0 >> 2)) * K + (c0 & 3) * 8;
    const ushort* bg1 = Bt + (size_t)(n0 + (c1 >> 2)) * K + (c1 & 3) * 8;
    ushort* la0 = &a_t[0][0] + w * 512;
    ushort* la1 = &a_t[0][0] + 2048 + w * 512;
    ushort* lb0 = &b_t[0][0] + w * 512;
    ushort* lb1 = &b_t[0][0] + 2048 + w * 512;

    floatx4 acc[2][8];
    floatx4 zero4 = {0.0f, 0.0f, 0.0f, 0.0f};
    #pragma unroll
    for (int mt = 0; mt < 2; mt++)
        #pragma unroll
        for (int nt = 0; nt < 8; nt++) acc[mt][nt] = zero4;

    union U8 { uint4 u4; short8 s8; };

    for (int k0 = 0; k0 < K; k0 += 32) {
        __syncthreads();
        glds16(ag0 + k0, la0);
        glds16(ag1 + k0, la1);
        glds16(bg0 + k0, lb0);
        glds16(bg1 + k0, lb1);
        __syncthreads();

        U8 af[2];
        #pragma unroll
        for (int mt = 0; mt < 2; mt++)
            af[mt].u4 = *(const uint4*)&a_t[w * 32 + mt * 16 + fm][quad * 8];
        #pragma unroll
        for (int nt = 0; nt < 8; nt++) {
            U8 bf;
            bf.u4 = *(const uint4*)&b_t[nt * 16 + fm][quad * 8];
            acc[0][nt] = __builtin_amdgcn_mfma_f32_16x16x32_bf16(af[0].s8, bf.s8, acc[0][nt], 0, 0, 0);
            acc[1][nt] = __builtin_amdgcn_mfma_f32_16x16x32_bf16(af[1].s8, bf.s8, acc[1][nt], 0, 0, 0);
        }
    }

    #pragma unroll
    for (int mt = 0; mt < 2; mt++)
        #pragma unroll
        for (int nt = 0; nt < 8; nt++)
            #pragma unroll
            for (int r = 0; r < 4; r++)
                C[(size_t)(m0 + w * 32 + mt * 16 + quad * 4 + r) * N + n0 + nt * 16 + fm] =
                    f2bf(acc[mt][nt][r]);
}

// ---------------------------------------------------------------------------
// Flash attention v7 (unchanged from r8, validated): 32x32x16 MFMA, slab
// layout, contiguous slab staging, in-block split-K (2 ks x 4 qg waves),
// software-pipelined softmax (QK(s)+exp(s) overlap PV(s-1)).
// ---------------------------------------------------------------------------
__global__ __launch_bounds__(512, 4) void attn_kernel(const ushort* __restrict__ q,
                                                      const ushort* __restrict__ kb,
                                                      const ushort* __restrict__ vt,
                                                      ushort* __restrict__ out) {
    __shared__ ushort smem[17408];          // 34.8 KB
    ushort* k_t = smem;                     // [ks][buf][oct8][pos32][8]
    ushort* v_t = smem + 8192;              // [ks][buf][oct4][d64][8]

    const int i0 = blockIdx.x * 128;
    const int h0 = blockIdx.y, b = blockIdx.z;
    const int tid = threadIdx.x, w = tid >> 6, lane = tid & 63;
    const int qg = w & 3;          // query group of 32 (0..3)
    const int ks = w >> 2;         // key half: 0 -> [0,1024), 1 -> [1024,2048)
    const int cq = lane & 31;      // C col = query; A row = position / d
    const int hi = lane >> 5;      // k-slice half within fragment

    union U8 { uint4 u4; short8 s8; };

    // Q B-frags: qf[dm] holds Q[q=cq][d = 16*dm + 8*hi + j]
    const ushort* qbase = q + (size_t)(b * 2048 + i0 + qg * 32 + cq) * 512 + h0 * 64 + hi * 8;
    U8 qf[4];
    #pragma unroll
    for (int dm = 0; dm < 4; dm++) qf[dm].u4 = *(const uint4*)(qbase + dm * 16);

    floatx16 acc0, acc1;           // O^T partials: d 0..31 (acc0), 32..63 (acc1)
    #pragma unroll
    for (int i = 0; i < 16; i++) { acc0[i] = 0.0f; acc1[i] = 0.0f; }
    float lsum = 0.0f;

    // Contiguous slab sources: K/V pre-formatted by gemm_qkv128.
    const ushort* kSrc = kb + (size_t)b * 131072 + ks * 65536 + lane * 8;
    const ushort* vSrc = vt + (size_t)b * 131072 + ks * 65536 + lane * 8;

    ushort* kT = k_t + ks * 4096;
    ushort* vT = v_t + ks * 4096;

    auto stageK = [&](int s, int buf) {
        glds16(kSrc + s * 2048 + qg * 512, kT + buf * 2048 + qg * 512);
    };
    auto stageV = [&](int s, int buf) {
        glds16(vSrc + s * 2048 + qg * 512, vT + buf * 2048 + qg * 512);
    };

    // QK^T + exp2 + pack -> P (key-permuted in layout)
    auto qk_exp = [&](int buf, U8& pb0, U8& pb1) {
        const int bo = buf * 2048;
        floatx16 st;
        #pragma unroll
        for (int i = 0; i < 16; i++) st[i] = -23.0831206f;   // -16*log2(e)
        #pragma unroll
        for (int dm = 0; dm < 4; dm++) {
            U8 kf;
            kf.u4 = *(const uint4*)&kT[bo + (2 * dm + hi) * 256 + cq * 8];
            st = __builtin_amdgcn_mfma_f32_32x32x16_bf16(kf.s8, qf[dm].s8, st, 0, 0, 0);
        }
        float p_[16];
        #pragma unroll
        for (int r = 0; r < 16; r++) p_[r] = __builtin_amdgcn_exp2f(st[r]);
        lsum += (((p_[0] + p_[1]) + (p_[2] + p_[3])) + ((p_[4] + p_[5]) + (p_[6] + p_[7])))
              + (((p_[8] + p_[9]) + (p_[10] + p_[11])) + ((p_[12] + p_[13]) + (p_[14] + p_[15])));
        pb0.u4.x = pk2(p_[0], p_[1]);   pb0.u4.y = pk2(p_[2], p_[3]);
        pb0.u4.z = pk2(p_[4], p_[5]);   pb0.u4.w = pk2(p_[6], p_[7]);
        pb1.u4.x = pk2(p_[8], p_[9]);   pb1.u4.y = pk2(p_[10], p_[11]);
        pb1.u4.z = pk2(p_[12], p_[13]); pb1.u4.w = pk2(p_[14], p_[15]);
    };

    // PV: O^T(d-tile) += V^T(key-slice) x P^T
    auto pv = [&](int buf, U8 pb0, U8 pb1) {
        const int bo = buf * 2048;
        U8 vf;
        vf.u4 = *(const uint4*)&vT[bo + (0 + hi) * 512 + cq * 8];
        acc0 = __builtin_amdgcn_mfma_f32_32x32x16_bf16(vf.s8, pb0.s8, acc0, 0, 0, 0);
        vf.u4 = *(const uint4*)&vT[bo + (2 + hi) * 512 + cq * 8];
        acc0 = __builtin_amdgcn_mfma_f32_32x32x16_bf16(vf.s8, pb1.s8, acc0, 0, 0, 0);
        vf.u4 = *(const uint4*)&vT[bo + (0 + hi) * 512 + (32 + cq) * 8];
        acc1 = __builtin_amdgcn_mfma_f32_32x32x16_bf16(vf.s8, pb0.s8, acc1, 0, 0, 0);
        vf.u4 = *(const uint4*)&vT[bo + (2 + hi) * 512 + (32 + cq) * 8];
        acc1 = __builtin_amdgcn_mfma_f32_32x32x16_bf16(vf.s8, pb1.s8, acc1, 0, 0, 0);
    };

    U8 pA0, pA1, pB0, pB1;         // P for even / odd steps (static names)

    // prologue: K(0) -> Kbuf0
    stageK(0, 0);
    __syncthreads();

    // interval 0: stage K(1), V(0); QK(0)->pA
    stageK(1, 1);
    stageV(0, 0);
    qk_exp(0, pA0, pA1);
    __syncthreads();

    // intervals 1..31, unrolled by 2 (odd s -> pB, even s -> pA)
    for (int s = 1; s < 32; s += 2) {
        if (s + 1 < 32) stageK(s + 1, 0);
        stageV(s, 1);
        qk_exp(1, pB0, pB1);
        pv(0, pA0, pA1);
        __syncthreads();

        if (s + 1 < 32) {
            if (s + 2 < 32) stageK(s + 2, 1);
            stageV(s + 1, 0);
            qk_exp(0, pA0, pA1);
            pv(1, pB0, pB1);
            __syncthreads();
        }
    }
    // epilogue: PV(31)
    pv(1, pB0, pB1);
    __syncthreads();               // all LDS reads done before combine overwrites

    // ---- split-K combine via LDS (stride-34 f32) ----
    float* row = (float*)smem + (qg * 64 + lane) * 34;
    if (ks == 1) {
        #pragma unroll
        for (int i = 0; i < 16; i++) { row[i] = acc0[i]; row[16 + i] = acc1[i]; }
        row[32] = lsum;
    }
    __syncthreads();
    if (ks == 1) return;
    #pragma unroll
    for (int i = 0; i < 16; i++) { acc0[i] += row[i]; acc1[i] += row[16 + i]; }
    lsum += row[32];
    lsum += __shfl_xor(lsum, 32);   // combine hi/lo position halves
    float li = 1.0f / fmaxf(lsum, 1e-30f);

    // write out: reg 4t+u of acc0 -> d = u + 8t + 4hi; acc1 -> +32
    ushort* ob = out + (size_t)(b * 2048 + i0 + qg * 32 + cq) * 512 + h0 * 64 + hi * 4;
    #pragma unroll
    for (int t = 0; t < 4; t++) {
        uint2 ov;
        ov.x = pk2(acc0[4 * t] * li, acc0[4 * t + 1] * li);
        ov.y = pk2(acc0[4 * t + 2] * li, acc0[4 * t + 3] * li);
        *(uint2*)(ob + t * 8) = ov;
        ov.x = pk2(acc1[4 * t] * li, acc1[4 * t + 1] * li);
        ov.y = pk2(acc1[4 * t + 2] * li, acc1[4 * t + 3] * li);
        *(uint2*)(ob + 32 + t * 8) = ov;
    }
}

// ---------------------------------------------------------------------------
// Memory plan (bf16 intermediates, ws_size needed = 16MB):
//   d_out: xn [0:16MB) (dead after gemm_qkv128) -> ao [0:8MB), woT [8:16MB)
//   ws:    qb [0:8), kb [8:9), vt [9:11), wcatT [11:12.25); y [0:16) after attn.
// Dispatches (6): prep, gemm_qkv128, wout_tr, attn, gemm_bt128, ln2.
// ---------------------------------------------------------------------------
extern "C" void kernel_launch(void* const* d_in, const int* in_sizes, int n_in,
                              void* d_out, int out_size, void* d_ws, size_t ws_size,
                              hipStream_t stream) {
    const void* x          = d_in[0];
    const void* norm_g     = d_in[1];
    const void* Wq         = d_in[2];
    const void* Wkv        = d_in[3];
    const void* Wout       = d_in[4];
    const void* out_norm_g = d_in[5];
    const ushort* probe = (const ushort*)d_in[0];
    ushort* ws = (ushort*)d_ws;

    const size_t M1 = 1024 * 1024 / 2;  // bf16 elems per MB
    ushort* xn    = (ushort*)d_out;
    ushort* ao    = (ushort*)d_out;
    ushort* woT   = (ushort*)((char*)d_out + (8u << 20));
    ushort* qb    = ws;
    ushort* kb    = ws + 8 * M1;
    ushort* vt    = ws + 9 * M1;
    ushort* wcatT = ws + 11 * M1;
    ushort* y     = ws;

    // prep: LN1 + Wq^T + Wkv^T fused
    prep_kernel<<<8832, 256, 0, stream>>>(x, norm_g, Wq, Wkv, xn, wcatT, probe);

    // fused q/k/v projection + l2norm + K/V slab formatting (128-tile)
    gemm_qkv128<<<dim3(5, 64), 256, 0, stream>>>(xn, wcatT, qb, kb, vt);

    // Wout^T -> d_out[8:16MB) (xn dead now)
    wout_tr_kernel<<<dim3(32, 16), 256, 0, stream>>>(Wout, woT, probe);

    // attention -> ao
    attn_kernel<<<dim3(16, 8, 4), 512, 0, stream>>>(qb, kb, vt, ao);

    // y = ao @ Wout  (128-tile, global_load_lds)
    gemm_bt128<<<dim3(8, 64), 256, 0, stream>>>(ao, woT, y, 8192, 1024, 512);

    // LN2: y -> final output
    ln2_kernel<<<8192, 256, 0, stream>>>(y, out_norm_g, d_out, probe);
}

// Round 11
// 202.133 us; speedup vs baseline: 1.1230x; 1.0066x over previous
//
#include <hip/hip_runtime.h>
#include <hip/hip_bf16.h>

typedef __attribute__((ext_vector_type(8))) short short8;
typedef __attribute__((ext_vector_type(4))) float floatx4;
typedef __attribute__((ext_vector_type(16))) float floatx16;

__device__ __forceinline__ float bf2f(ushort u) {
    return __uint_as_float(((unsigned int)u) << 16);
}
__device__ __forceinline__ ushort f2bf(float f) {
    unsigned int u = __float_as_uint(f);
    unsigned int r = (u + 0x7FFFu + ((u >> 16) & 1u)) >> 16;
    return (ushort)r;
}
// packed f32x2 -> bf16x2
__device__ __forceinline__ unsigned int pk2(float a, float b) {
    union { __hip_bfloat162 h; unsigned int u; } cv;
    cv.h = __float22bfloat162_rn(make_float2(a, b));
    return cv.u;
}
__device__ __forceinline__ float scrub(float v, float lim) {
    return fminf(fmaxf(v, -lim), lim);
}
// async global->LDS, 16B per lane (lane i lands at wave-uniform lds base + 16*i)
__device__ __forceinline__ void glds16(const ushort* g, ushort* l) {
    __builtin_amdgcn_global_load_lds((const __attribute__((address_space(1))) void*)g,
                                     (__attribute__((address_space(3))) void*)l, 16, 0, 0);
}

// Wave-uniform dtype probe on x: bf16 N(0,1) data has exponent byte in [117,131]
// ~99% at even ushort indices; fp32-as-ushort gives ~6%. 32 samples, thr 16.
__device__ __forceinline__ bool detect_bf16(const ushort* __restrict__ probe) {
    const int lane = threadIdx.x & 63;
    ushort u = probe[(lane & 31) * 2];
    int e = (u >> 7) & 0xFF;
    bool pl = (e >= 117) && (e <= 131) && (lane < 32);
    return __popcll(__ballot(pl)) >= 16;
}

// ---------------------------------------------------------------------------
// Transpose helper (256 threads).
// ---------------------------------------------------------------------------
__device__ __forceinline__ void do_transpose(const void* __restrict__ in,
                                             ushort* __restrict__ out,
                                             int bx, int by, int in_rs, int out_rs,
                                             bool ib, ushort* tile /*32x33*/) {
    const int tx = threadIdx.x & 31, ty = threadIdx.x >> 5;
    #pragma unroll
    for (int rr = 0; rr < 32; rr += 8) {
        size_t idx = (size_t)(by * 32 + ty + rr) * in_rs + bx * 32 + tx;
        float v = ib ? bf2f(((const ushort*)in)[idx]) : ((const float*)in)[idx];
        tile[(ty + rr) * 33 + tx] = f2bf(scrub(v, 1e8f));
    }
    __syncthreads();
    #pragma unroll
    for (int rr = 0; rr < 32; rr += 8) {
        int r = bx * 32 + ty + rr;
        int c = by * 32 + tx;
        out[(size_t)r * out_rs + c] = tile[tx * 33 + (ty + rr)];
    }
}

// ---------------------------------------------------------------------------
// Wave-local LN row: 1 row per wave, 16 elems/lane, shfl-only reduction.
// Loads x row + gamma (dtype per flag), LayerNorms, writes bf16 row.
// ---------------------------------------------------------------------------
__device__ __forceinline__ void ln_row_wave(const void* __restrict__ xin,
                                            const void* __restrict__ gin,
                                            ushort* __restrict__ xn,
                                            int row, int lane, bool ib) {
    float v[16], g[16];
    if (ib) {
        #pragma unroll
        for (int c = 0; c < 4; c++) {
            uint2 u  = *(const uint2*)((const ushort*)xin + (size_t)row * 1024 + c * 256 + lane * 4);
            uint2 gu = *(const uint2*)((const ushort*)gin + c * 256 + lane * 4);
            v[c*4+0] = bf2f((ushort)(u.x & 0xFFFF));  v[c*4+1] = bf2f((ushort)(u.x >> 16));
            v[c*4+2] = bf2f((ushort)(u.y & 0xFFFF));  v[c*4+3] = bf2f((ushort)(u.y >> 16));
            g[c*4+0] = bf2f((ushort)(gu.x & 0xFFFF)); g[c*4+1] = bf2f((ushort)(gu.x >> 16));
            g[c*4+2] = bf2f((ushort)(gu.y & 0xFFFF)); g[c*4+3] = bf2f((ushort)(gu.y >> 16));
        }
    } else {
        #pragma unroll
        for (int c = 0; c < 4; c++) {
            float4 xv = *(const float4*)((const float*)xin + (size_t)row * 1024 + c * 256 + lane * 4);
            float4 gv = *(const float4*)((const float*)gin + c * 256 + lane * 4);
            v[c*4+0] = xv.x; v[c*4+1] = xv.y; v[c*4+2] = xv.z; v[c*4+3] = xv.w;
            g[c*4+0] = gv.x; g[c*4+1] = gv.y; g[c*4+2] = gv.z; g[c*4+3] = gv.w;
        }
    }
    #pragma unroll
    for (int i = 0; i < 16; i++) { v[i] = scrub(v[i], 1e8f); g[i] = scrub(g[i], 1e8f); }

    float s = 0.0f, sq = 0.0f;
    #pragma unroll
    for (int i = 0; i < 16; i++) { s += v[i]; sq += v[i] * v[i]; }
    #pragma unroll
    for (int off = 1; off < 64; off <<= 1) {
        s  += __shfl_xor(s, off);
        sq += __shfl_xor(sq, off);
    }
    float mean = s * (1.0f / 1024.0f);
    float var  = sq * (1.0f / 1024.0f) - mean * mean;
    float rstd = rsqrtf(fmaxf(var, 0.0f) + 1e-5f);

    #pragma unroll
    for (int c = 0; c < 4; c++) {
        uint2 ov;
        ov.x = pk2((v[c*4+0] - mean) * rstd * g[c*4+0], (v[c*4+1] - mean) * rstd * g[c*4+1]);
        ov.y = pk2((v[c*4+2] - mean) * rstd * g[c*4+2], (v[c*4+3] - mean) * rstd * g[c*4+3]);
        *(uint2*)(xn + (size_t)row * 1024 + c * 256 + lane * 4) = ov;
    }
}

// ---------------------------------------------------------------------------
// prep v2: wave-per-row LN1 (blocks 0..2047, 4 rows/block, no barriers)
// + Wq^T (2048..2559) + Wkv^T (2560..2687) + optionally Wout^T (2688..3199,
// only when woT lives in d_out[16:17MB) — fp32-output path).
// ---------------------------------------------------------------------------
__global__ __launch_bounds__(256) void prep_kernel(const void* __restrict__ xin,
                                                   const void* __restrict__ gin,
                                                   const void* __restrict__ Wq,
                                                   const void* __restrict__ Wkv,
                                                   const void* __restrict__ Wout,
                                                   ushort* __restrict__ xn,
                                                   ushort* __restrict__ wcatT,
                                                   ushort* __restrict__ woT,
                                                   const ushort* __restrict__ probe) {
    const bool ib = detect_bf16(probe);
    const int id = blockIdx.x;
    __shared__ ushort tile[32 * 33];

    if (id >= 2048) {
        int t = id - 2048;
        if (t < 512) {                          // Wq[1024][512] -> wcatT[0:512)[1024]
            do_transpose(Wq, wcatT, t & 15, t >> 4, 512, 1024, ib, tile);
        } else if (t < 640) {                   // Wkv[1024][128] -> wcatT[512:640)[1024]
            t -= 512;
            do_transpose(Wkv, wcatT + (size_t)512 * 1024, t & 3, t >> 2, 128, 1024, ib, tile);
        } else {                                // Wout[512][1024] -> woT[1024][512]
            t -= 640;
            do_transpose(Wout, woT, t & 31, t >> 5, 1024, 512, ib, tile);
        }
        return;
    }

    const int w = threadIdx.x >> 6, lane = threadIdx.x & 63;
    ln_row_wave(xin, gin, xn, id * 4 + w, lane, ib);
}

// ---------------------------------------------------------------------------
// Standalone Wout transpose (bf16-output fallback path only: woT must wait
// for gemm_qkv because it lives in d_out[8:16MB) under xn).
// ---------------------------------------------------------------------------
__global__ __launch_bounds__(256) void wout_tr_kernel(const void* __restrict__ Wout,
                                                      ushort* __restrict__ woT,
                                                      const ushort* __restrict__ probe) {
    const bool ib = detect_bf16(probe);
    __shared__ ushort tile[32 * 33];
    do_transpose(Wout, woT, blockIdx.x, blockIdx.y, 1024, 512, ib, tile);
}

// ---------------------------------------------------------------------------
// LN2 v2: wave-per-row (4 rows/block, grid 2048). Input y bf16; gamma +
// OUTPUT dtype detected.
// ---------------------------------------------------------------------------
__global__ __launch_bounds__(256) void ln2_kernel(const ushort* __restrict__ y,
                                                  const void* __restrict__ gin,
                                                  void* __restrict__ out,
                                                  const ushort* __restrict__ probe) {
    const bool ob = detect_bf16(probe);
    const int w = threadIdx.x >> 6, lane = threadIdx.x & 63;
    const int row = blockIdx.x * 4 + w;

    float v[16], g[16];
    #pragma unroll
    for (int c = 0; c < 4; c++) {
        uint2 u = *(const uint2*)(y + (size_t)row * 1024 + c * 256 + lane * 4);
        v[c*4+0] = bf2f((ushort)(u.x & 0xFFFF)); v[c*4+1] = bf2f((ushort)(u.x >> 16));
        v[c*4+2] = bf2f((ushort)(u.y & 0xFFFF)); v[c*4+3] = bf2f((ushort)(u.y >> 16));
    }
    if (ob) {
        #pragma unroll
        for (int c = 0; c < 4; c++) {
            uint2 gu = *(const uint2*)((const ushort*)gin + c * 256 + lane * 4);
            g[c*4+0] = bf2f((ushort)(gu.x & 0xFFFF)); g[c*4+1] = bf2f((ushort)(gu.x >> 16));
            g[c*4+2] = bf2f((ushort)(gu.y & 0xFFFF)); g[c*4+3] = bf2f((ushort)(gu.y >> 16));
        }
    } else {
        #pragma unroll
        for (int c = 0; c < 4; c++) {
            float4 gv = *(const float4*)((const float*)gin + c * 256 + lane * 4);
            g[c*4+0] = gv.x; g[c*4+1] = gv.y; g[c*4+2] = gv.z; g[c*4+3] = gv.w;
        }
    }
    #pragma unroll
    for (int i = 0; i < 16; i++) { v[i] = scrub(v[i], 1e8f); g[i] = scrub(g[i], 1e8f); }

    float s = 0.0f, sq = 0.0f;
    #pragma unroll
    for (int i = 0; i < 16; i++) { s += v[i]; sq += v[i] * v[i]; }
    #pragma unroll
    for (int off = 1; off < 64; off <<= 1) {
        s  += __shfl_xor(s, off);
        sq += __shfl_xor(sq, off);
    }
    float mean = s * (1.0f / 1024.0f);
    float var  = sq * (1.0f / 1024.0f) - mean * mean;
    float rstd = rsqrtf(fmaxf(var, 0.0f) + 1e-5f);

    if (ob) {
        #pragma unroll
        for (int c = 0; c < 4; c++) {
            uint2 ov;
            ov.x = pk2((v[c*4+0] - mean) * rstd * g[c*4+0], (v[c*4+1] - mean) * rstd * g[c*4+1]);
            ov.y = pk2((v[c*4+2] - mean) * rstd * g[c*4+2], (v[c*4+3] - mean) * rstd * g[c*4+3]);
            *(uint2*)((ushort*)out + (size_t)row * 1024 + c * 256 + lane * 4) = ov;
        }
    } else {
        #pragma unroll
        for (int c = 0; c < 4; c++) {
            float4 ov = make_float4((v[c*4+0] - mean) * rstd * g[c*4+0],
                                    (v[c*4+1] - mean) * rstd * g[c*4+1],
                                    (v[c*4+2] - mean) * rstd * g[c*4+2],
                                    (v[c*4+3] - mean) * rstd * g[c*4+3]);
            *(float4*)((float*)out + (size_t)row * 1024 + c * 256 + lane * 4) = ov;
        }
    }
}

// ---------------------------------------------------------------------------
// Fused QKV GEMM: 128x128 m97-style tile. grid (5,64) = 320 blocks, 256 thr.
//   bx<4 : q tiles (heads 2bx, 2bx+1) -> per-head l2norm * 4*log2(e).
//   bx==4: nt 0-3 = k (l2norm, scale 4, SLAB), nt 4-7 = v (SLAB).
// Slabs (validated r5-r10):
//   K: kb[b][kblk32][d-oct8][pos32][e8], pos = bitswap23(key&31)
//   V: vt[b][kblk32][k-oct4][d64][kk8]
// ---------------------------------------------------------------------------
__global__ __launch_bounds__(256) void gemm_qkv128(const ushort* __restrict__ A,
                                                   const ushort* __restrict__ Bt,
                                                   ushort* __restrict__ qb,
                                                   ushort* __restrict__ kb,
                                                   ushort* __restrict__ vt) {
    __shared__ ushort a_t[128][32];
    __shared__ ushort b_t[128][32];

    const int bx = blockIdx.x;
    const int n0 = bx * 128, m0 = blockIdx.y * 128;
    const int tid = threadIdx.x;
    const int w = tid >> 6, lane = tid & 63;
    const int fm = lane & 15, quad = lane >> 4;
    const int K = 1024;

    const int c0 = tid, c1 = tid + 256;
    const ushort* ag0 = A + (size_t)(m0 + (c0 >> 2)) * K + (c0 & 3) * 8;
    const ushort* ag1 = A + (size_t)(m0 + (c1 >> 2)) * K + (c1 & 3) * 8;
    const ushort* bg0 = Bt + (size_t)(n0 + (c0 >> 2)) * K + (c0 & 3) * 8;
    const ushort* bg1 = Bt + (size_t)(n0 + (c1 >> 2)) * K + (c1 & 3) * 8;
    ushort* la0 = &a_t[0][0] + w * 512;
    ushort* la1 = &a_t[0][0] + 2048 + w * 512;
    ushort* lb0 = &b_t[0][0] + w * 512;
    ushort* lb1 = &b_t[0][0] + 2048 + w * 512;

    floatx4 acc[2][8];
    floatx4 zero4 = {0.0f, 0.0f, 0.0f, 0.0f};
    #pragma unroll
    for (int mt = 0; mt < 2; mt++)
        #pragma unroll
        for (int nt = 0; nt < 8; nt++) acc[mt][nt] = zero4;

    union U8 { uint4 u4; short8 s8; };

    for (int k0 = 0; k0 < K; k0 += 32) {
        __syncthreads();
        glds16(ag0 + k0, la0);
        glds16(ag1 + k0, la1);
        glds16(bg0 + k0, lb0);
        glds16(bg1 + k0, lb1);
        __syncthreads();

        U8 af[2];
        #pragma unroll
        for (int mt = 0; mt < 2; mt++)
            af[mt].u4 = *(const uint4*)&a_t[w * 32 + mt * 16 + fm][quad * 8];
        #pragma unroll
        for (int nt = 0; nt < 8; nt++) {
            U8 bf;
            bf.u4 = *(const uint4*)&b_t[nt * 16 + fm][quad * 8];
            acc[0][nt] = __builtin_amdgcn_mfma_f32_16x16x32_bf16(af[0].s8, bf.s8, acc[0][nt], 0, 0, 0);
            acc[1][nt] = __builtin_amdgcn_mfma_f32_16x16x32_bf16(af[1].s8, bf.s8, acc[1][nt], 0, 0, 0);
        }
    }

    if (bx < 4) {
        // q epilogue: two heads per tile; per-row l2norm over each head's 64 cols.
        const float qsc = 5.7707801636f;       // 4*log2(e)
        #pragma unroll
        for (int mt = 0; mt < 2; mt++) {
            float scA[4], scB[4];
            #pragma unroll
            for (int r = 0; r < 4; r++) {
                float sa = acc[mt][0][r] * acc[mt][0][r] + acc[mt][1][r] * acc[mt][1][r]
                         + acc[mt][2][r] * acc[mt][2][r] + acc[mt][3][r] * acc[mt][3][r];
                float sb = acc[mt][4][r] * acc[mt][4][r] + acc[mt][5][r] * acc[mt][5][r]
                         + acc[mt][6][r] * acc[mt][6][r] + acc[mt][7][r] * acc[mt][7][r];
                sa += __shfl_xor(sa, 1); sb += __shfl_xor(sb, 1);
                sa += __shfl_xor(sa, 2); sb += __shfl_xor(sb, 2);
                sa += __shfl_xor(sa, 4); sb += __shfl_xor(sb, 4);
                sa += __shfl_xor(sa, 8); sb += __shfl_xor(sb, 8);
                scA[r] = qsc / fmaxf(sqrtf(sa), 1e-12f);
                scB[r] = qsc / fmaxf(sqrtf(sb), 1e-12f);
            }
            #pragma unroll
            for (int nt = 0; nt < 8; nt++)
                #pragma unroll
                for (int r = 0; r < 4; r++)
                    qb[(size_t)(m0 + w * 32 + mt * 16 + quad * 4 + r) * 512 + n0 + nt * 16 + fm] =
                        f2bf(acc[mt][nt][r] * ((nt < 4) ? scA[r] : scB[r]));
        }
    } else {
        // k (nt 0-3) + v (nt 4-7) slab epilogue. One wave = one 32-key block.
        const int bb = m0 >> 11;
        const int kblk = ((m0 & 2047) >> 5) + w;
        const int qsw = ((quad & 1) << 1) | (quad >> 1); // bitswap23 of quad
        #pragma unroll
        for (int mt = 0; mt < 2; mt++) {
            float sck[4];
            #pragma unroll
            for (int r = 0; r < 4; r++) {
                float ss = acc[mt][0][r] * acc[mt][0][r] + acc[mt][1][r] * acc[mt][1][r]
                         + acc[mt][2][r] * acc[mt][2][r] + acc[mt][3][r] * acc[mt][3][r];
                ss += __shfl_xor(ss, 1);
                ss += __shfl_xor(ss, 2);
                ss += __shfl_xor(ss, 4);
                ss += __shfl_xor(ss, 8);
                sck[r] = 4.0f / fmaxf(sqrtf(ss), 1e-12f);
            }
            ushort* kop = kb + (size_t)bb * 131072 + kblk * 2048
                        + mt * 128 + qsw * 32 + (fm & 7);
            #pragma unroll
            for (int nt = 0; nt < 4; nt++) {
                const int oct = nt * 2 + (fm >> 3);      // d = nt*16 + fm
                #pragma unroll
                for (int r = 0; r < 4; r++)
                    kop[oct * 256 + r * 8] = f2bf(acc[mt][nt][r] * sck[r]);
            }
            const int koct = mt * 2 + (quad >> 1);
            ushort* vb = vt + (size_t)bb * 131072 + kblk * 2048 + koct * 512 + (quad & 1) * 4;
            #pragma unroll
            for (int nt = 4; nt < 8; nt++) {
                uint2 pv;
                pv.x = pk2(acc[mt][nt][0], acc[mt][nt][1]);
                pv.y = pk2(acc[mt][nt][2], acc[mt][nt][3]);
                *(uint2*)(vb + ((nt - 4) * 16 + fm) * 8) = pv;
            }
        }
    }
}

// ---------------------------------------------------------------------------
// Out-projection GEMM, m97-style: 128x128 tile, BK=32, global_load_lds w=16.
// ---------------------------------------------------------------------------
__global__ __launch_bounds__(256) void gemm_bt128(const ushort* __restrict__ A,
                                                  const ushort* __restrict__ Bt,
                                                  ushort* __restrict__ C,
                                                  int M, int N, int K) {
    __shared__ ushort a_t[128][32];
    __shared__ ushort b_t[128][32];

    const int n0 = blockIdx.x * 128, m0 = blockIdx.y * 128;
    const int tid = threadIdx.x;
    const int w = tid >> 6, lane = tid & 63;
    const int fm = lane & 15, quad = lane >> 4;

    const int c0 = tid, c1 = tid + 256;
    const ushort* ag0 = A + (size_t)(m0 + (c0 >> 2)) * K + (c0 & 3) * 8;
    const ushort* ag1 = A + (size_t)(m0 + (c1 >> 2)) * K + (c1 & 3) * 8;
    const ushort* bg0 = Bt + (size_t)(n0 + (c0 >> 2)) * K + (c0 & 3) * 8;
    const ushort* bg1 = Bt + (size_t)(n0 + (c1 >> 2)) * K + (c1 & 3) * 8;
    ushort* la0 = &a_t[0][0] + w * 512;
    ushort* la1 = &a_t[0][0] + 2048 + w * 512;
    ushort* lb0 = &b_t[0][0] + w * 512;
    ushort* lb1 = &b_t[0][0] + 2048 + w * 512;

    floatx4 acc[2][8];
    floatx4 zero4 = {0.0f, 0.0f, 0.0f, 0.0f};
    #pragma unroll
    for (int mt = 0; mt < 2; mt++)
        #pragma unroll
        for (int nt = 0; nt < 8; nt++) acc[mt][nt] = zero4;

    union U8 { uint4 u4; short8 s8; };

    for (int k0 = 0; k0 < K; k0 += 32) {
        __syncthreads();
        glds16(ag0 + k0, la0);
        glds16(ag1 + k0, la1);
        glds16(bg0 + k0, lb0);
        glds16(bg1 + k0, lb1);
        __syncthreads();

        U8 af[2];
        #pragma unroll
        for (int mt = 0; mt < 2; mt++)
            af[mt].u4 = *(const uint4*)&a_t[w * 32 + mt * 16 + fm][quad * 8];
        #pragma unroll
        for (int nt = 0; nt < 8; nt++) {
            U8 bf;
            bf.u4 = *(const uint4*)&b_t[nt * 16 + fm][quad * 8];
            acc[0][nt] = __builtin_amdgcn_mfma_f32_16x16x32_bf16(af[0].s8, bf.s8, acc[0][nt], 0, 0, 0);
            acc[1][nt] = __builtin_amdgcn_mfma_f32_16x16x32_bf16(af[1].s8, bf.s8, acc[1][nt], 0, 0, 0);
        }
    }

    #pragma unroll
    for (int mt = 0; mt < 2; mt++)
        #pragma unroll
        for (int nt = 0; nt < 8; nt++)
            #pragma unroll
            for (int r = 0; r < 4; r++)
                C[(size_t)(m0 + w * 32 + mt * 16 + quad * 4 + r) * N + n0 + nt * 16 + fm] =
                    f2bf(acc[mt][nt][r]);
}

// ---------------------------------------------------------------------------
// Flash attention v7 (unchanged, validated r8/r10): 32x32x16 MFMA, slab
// layout, contiguous slab staging, in-block split-K (2 ks x 4 qg waves),
// software-pipelined softmax (QK(s)+exp(s) overlap PV(s-1)).
// ---------------------------------------------------------------------------
__global__ __launch_bounds__(512, 4) void attn_kernel(const ushort* __restrict__ q,
                                                      const ushort* __restrict__ kb,
                                                      const ushort* __restrict__ vt,
                                                      ushort* __restrict__ out) {
    __shared__ ushort smem[17408];          // 34.8 KB
    ushort* k_t = smem;                     // [ks][buf][oct8][pos32][8]
    ushort* v_t = smem + 8192;              // [ks][buf][oct4][d64][8]

    const int i0 = blockIdx.x * 128;
    const int h0 = blockIdx.y, b = blockIdx.z;
    const int tid = threadIdx.x, w = tid >> 6, lane = tid & 63;
    const int qg = w & 3;          // query group of 32 (0..3)
    const int ks = w >> 2;         // key half: 0 -> [0,1024), 1 -> [1024,2048)
    const int cq = lane & 31;      // C col = query; A row = position / d
    const int hi = lane >> 5;      // k-slice half within fragment

    union U8 { uint4 u4; short8 s8; };

    // Q B-frags: qf[dm] holds Q[q=cq][d = 16*dm + 8*hi + j]
    const ushort* qbase = q + (size_t)(b * 2048 + i0 + qg * 32 + cq) * 512 + h0 * 64 + hi * 8;
    U8 qf[4];
    #pragma unroll
    for (int dm = 0; dm < 4; dm++) qf[dm].u4 = *(const uint4*)(qbase + dm * 16);

    floatx16 acc0, acc1;           // O^T partials: d 0..31 (acc0), 32..63 (acc1)
    #pragma unroll
    for (int i = 0; i < 16; i++) { acc0[i] = 0.0f; acc1[i] = 0.0f; }
    float lsum = 0.0f;

    // Contiguous slab sources: K/V pre-formatted by gemm_qkv128.
    const ushort* kSrc = kb + (size_t)b * 131072 + ks * 65536 + lane * 8;
    const ushort* vSrc = vt + (size_t)b * 131072 + ks * 65536 + lane * 8;

    ushort* kT = k_t + ks * 4096;
    ushort* vT = v_t + ks * 4096;

    auto stageK = [&](int s, int buf) {
        glds16(kSrc + s * 2048 + qg * 512, kT + buf * 2048 + qg * 512);
    };
    auto stageV = [&](int s, int buf) {
        glds16(vSrc + s * 2048 + qg * 512, vT + buf * 2048 + qg * 512);
    };

    // QK^T + exp2 + pack -> P (key-permuted in layout)
    auto qk_exp = [&](int buf, U8& pb0, U8& pb1) {
        const int bo = buf * 2048;
        floatx16 st;
        #pragma unroll
        for (int i = 0; i < 16; i++) st[i] = -23.0831206f;   // -16*log2(e)
        #pragma unroll
        for (int dm = 0; dm < 4; dm++) {
            U8 kf;
            kf.u4 = *(const uint4*)&kT[bo + (2 * dm + hi) * 256 + cq * 8];
            st = __builtin_amdgcn_mfma_f32_32x32x16_bf16(kf.s8, qf[dm].s8, st, 0, 0, 0);
        }
        float p_[16];
        #pragma unroll
        for (int r = 0; r < 16; r++) p_[r] = __builtin_amdgcn_exp2f(st[r]);
        lsum += (((p_[0] + p_[1]) + (p_[2] + p_[3])) + ((p_[4] + p_[5]) + (p_[6] + p_[7])))
              + (((p_[8] + p_[9]) + (p_[10] + p_[11])) + ((p_[12] + p_[13]) + (p_[14] + p_[15])));
        pb0.u4.x = pk2(p_[0], p_[1]);   pb0.u4.y = pk2(p_[2], p_[3]);
        pb0.u4.z = pk2(p_[4], p_[5]);   pb0.u4.w = pk2(p_[6], p_[7]);
        pb1.u4.x = pk2(p_[8], p_[9]);   pb1.u4.y = pk2(p_[10], p_[11]);
        pb1.u4.z = pk2(p_[12], p_[13]); pb1.u4.w = pk2(p_[14], p_[15]);
    };

    // PV: O^T(d-tile) += V^T(key-slice) x P^T
    auto pv = [&](int buf, U8 pb0, U8 pb1) {
        const int bo = buf * 2048;
        U8 vf;
        vf.u4 = *(const uint4*)&vT[bo + (0 + hi) * 512 + cq * 8];
        acc0 = __builtin_amdgcn_mfma_f32_32x32x16_bf16(vf.s8, pb0.s8, acc0, 0, 0, 0);
        vf.u4 = *(const uint4*)&vT[bo + (2 + hi) * 512 + cq * 8];
        acc0 = __builtin_amdgcn_mfma_f32_32x32x16_bf16(vf.s8, pb1.s8, acc0, 0, 0, 0);
        vf.u4 = *(const uint4*)&vT[bo + (0 + hi) * 512 + (32 + cq) * 8];
        acc1 = __builtin_amdgcn_mfma_f32_32x32x16_bf16(vf.s8, pb0.s8, acc1, 0, 0, 0);
        vf.u4 = *(const uint4*)&vT[bo + (2 + hi) * 512 + (32 + cq) * 8];
        acc1 = __builtin_amdgcn_mfma_f32_32x32x16_bf16(vf.s8, pb1.s8, acc1, 0, 0, 0);
    };

    U8 pA0, pA1, pB0, pB1;         // P for even / odd steps (static names)

    // prologue: K(0) -> Kbuf0
    stageK(0, 0);
    __syncthreads();

    // interval 0: stage K(1), V(0); QK(0)->pA
    stageK(1, 1);
    stageV(0, 0);
    qk_exp(0, pA0, pA1);
    __syncthreads();

    // intervals 1..31, unrolled by 2 (odd s -> pB, even s -> pA)
    for (int s = 1; s < 32; s += 2) {
        if (s + 1 < 32) stageK(s + 1, 0);
        stageV(s, 1);
        qk_exp(1, pB0, pB1);
        pv(0, pA0, pA1);
        __syncthreads();

        if (s + 1 < 32) {
            if (s + 2 < 32) stageK(s + 2, 1);
            stageV(s + 1, 0);
            qk_exp(0, pA0, pA1);
            pv(1, pB0, pB1);
            __syncthreads();
        }
    }
    // epilogue: PV(31)
    pv(1, pB0, pB1);
    __syncthreads();               // all LDS reads done before combine overwrites

    // ---- split-K combine via LDS (stride-34 f32) ----
    float* row = (float*)smem + (qg * 64 + lane) * 34;
    if (ks == 1) {
        #pragma unroll
        for (int i = 0; i < 16; i++) { row[i] = acc0[i]; row[16 + i] = acc1[i]; }
        row[32] = lsum;
    }
    __syncthreads();
    if (ks == 1) return;
    #pragma unroll
    for (int i = 0; i < 16; i++) { acc0[i] += row[i]; acc1[i] += row[16 + i]; }
    lsum += row[32];
    lsum += __shfl_xor(lsum, 32);   // combine hi/lo position halves
    float li = 1.0f / fmaxf(lsum, 1e-30f);

    // write out: reg 4t+u of acc0 -> d = u + 8t + 4hi; acc1 -> +32
    ushort* ob = out + (size_t)(b * 2048 + i0 + qg * 32 + cq) * 512 + h0 * 64 + hi * 4;
    #pragma unroll
    for (int t = 0; t < 4; t++) {
        uint2 ov;
        ov.x = pk2(acc0[4 * t] * li, acc0[4 * t + 1] * li);
        ov.y = pk2(acc0[4 * t + 2] * li, acc0[4 * t + 3] * li);
        *(uint2*)(ob + t * 8) = ov;
        ov.x = pk2(acc1[4 * t] * li, acc1[4 * t + 1] * li);
        ov.y = pk2(acc1[4 * t + 2] * li, acc1[4 * t + 3] * li);
        *(uint2*)(ob + 32 + t * 8) = ov;
    }
}

// ---------------------------------------------------------------------------
// Memory plan:
//   fp32-output path (out_size >= 17MB, the benched case):
//     d_out: xn [0:16MB) -> ao [0:8MB);  woT [16:17MB) (written by prep!)
//     5 dispatches: prep(+woT), gemm_qkv128, attn, gemm_bt128, ln2.
//   bf16-output fallback (d_out only 16MB):
//     woT [8:16MB) as before; 6 dispatches with separate wout_tr after qkv.
//   ws: qb [0:8), kb [8:9), vt [9:11), wcatT [11:12.25); y [0:16) after attn.
// ---------------------------------------------------------------------------
extern "C" void kernel_launch(void* const* d_in, const int* in_sizes, int n_in,
                              void* d_out, int out_size, void* d_ws, size_t ws_size,
                              hipStream_t stream) {
    const void* x          = d_in[0];
    const void* norm_g     = d_in[1];
    const void* Wq         = d_in[2];
    const void* Wkv        = d_in[3];
    const void* Wout       = d_in[4];
    const void* out_norm_g = d_in[5];
    const ushort* probe = (const ushort*)d_in[0];
    ushort* ws = (ushort*)d_ws;

    const size_t M1 = 1024 * 1024 / 2;  // bf16 elems per MB
    ushort* xn    = (ushort*)d_out;
    ushort* ao    = (ushort*)d_out;
    ushort* qb    = ws;
    ushort* kb    = ws + 8 * M1;
    ushort* vt    = ws + 9 * M1;
    ushort* wcatT = ws + 11 * M1;
    ushort* y     = ws;

    const bool big_out = out_size >= (17 << 20);
    ushort* woT = big_out ? (ushort*)((char*)d_out + (16u << 20))
                          : (ushort*)((char*)d_out + (8u << 20));

    // prep: LN1 (wave-per-row) + Wq^T + Wkv^T (+ Wout^T when woT is out of
    // xn's way in d_out[16:17MB))
    prep_kernel<<<big_out ? 3200 : 2688, 256, 0, stream>>>(
        x, norm_g, Wq, Wkv, Wout, xn, wcatT, woT, probe);

    // fused q/k/v projection + l2norm + K/V slab formatting (128-tile)
    gemm_qkv128<<<dim3(5, 64), 256, 0, stream>>>(xn, wcatT, qb, kb, vt);

    // bf16-output fallback: Wout^T must wait for gemm_qkv (xn dies then)
    if (!big_out)
        wout_tr_kernel<<<dim3(32, 16), 256, 0, stream>>>(Wout, woT, probe);

    // attention -> ao
    attn_kernel<<<dim3(16, 8, 4), 512, 0, stream>>>(qb, kb, vt, ao);

    // y = ao @ Wout  (128-tile, global_load_lds)
    gemm_bt128<<<dim3(8, 64), 256, 0, stream>>>(ao, woT, y, 8192, 1024, 512);

    // LN2: y -> final output (wave-per-row)
    ln2_kernel<<<2048, 256, 0, stream>>>(y, out_norm_g, d_out, probe);
}